// Round 9
// baseline (1145.691 us; speedup 1.0000x reference)
//
#include <hip/hip_runtime.h>

#define BB 2
#define HH 128
#define WW 256
#define CC 768
#define NB 8
#define BS 96
#define WKEPT 65
#define NPTS (BB*HH*WKEPT)        // 16640 kept (b,h,w') points
#define NTOT ((size_t)BB*HH*WW*CC) // 50331648
#define TWOPI 6.283185307179586f

typedef __attribute__((ext_vector_type(8))) short bf16x8;
typedef __attribute__((ext_vector_type(4))) float f32x4;

__device__ __forceinline__ unsigned short f2bf(float f) {
    unsigned int u = __float_as_uint(f);
    u += 0x7fffu + ((u >> 16) & 1u);      // round-to-nearest-even
    return (unsigned short)(u >> 16);
}
__device__ __forceinline__ float bf2f(unsigned short s) {
    return __uint_as_float((unsigned int)s << 16);
}

// ---------------------------------------------------------------------------
// K0: precombine weights into TRANSPOSED bf16 hi/lo pairs for MFMA
// (unchanged from round 8).
// ---------------------------------------------------------------------------
__global__ __launch_bounds__(256) void k_weights(
    const float* __restrict__ w1, const float* __restrict__ w2,
    const float* __restrict__ b2,
    unsigned short* __restrict__ W10h, unsigned short* __restrict__ W10l,
    unsigned short* __restrict__ W11h, unsigned short* __restrict__ W11l,
    unsigned short* __restrict__ WKPh, unsigned short* __restrict__ WKPl,
    unsigned short* __restrict__ WKMh, unsigned short* __restrict__ WKMl,
    float* __restrict__ BEFF)
{
    const int n = blockIdx.x;
    const int tid = threadIdx.x;
    __shared__ float m_s[BS*BS];

    const float* w2a = w2 + (size_t)(0*NB + n)*BS*BS;
    const float* w2b = w2 + (size_t)(1*NB + n)*BS*BS;
    for (int idx = tid; idx < BS*BS; idx += 256)
        m_s[idx] = 0.5f*(w2a[idx] - w2b[idx]);

    const float* w1a = w1 + (size_t)(0*NB + n)*BS*BS;
    const float* w1b = w1 + (size_t)(1*NB + n)*BS*BS;
    for (int idx = tid; idx < BS*BS; idx += 256) {
        int o = idx / BS, k = idx - o*BS;          // dest [o][k]
        float v0 = w1a[k*BS + o];
        unsigned short h0 = f2bf(v0);
        unsigned short l0 = f2bf(v0 - bf2f(h0));
        W10h[n*BS*BS + idx] = h0;  W10l[n*BS*BS + idx] = l0;
        float v1 = w1b[k*BS + o];
        unsigned short h1 = f2bf(v1);
        unsigned short l1 = f2bf(v1 - bf2f(h1));
        W11h[n*BS*BS + idx] = h1;  W11l[n*BS*BS + idx] = l1;
    }
    __syncthreads();

    for (int idx = tid; idx < BS*BS; idx += 256) {
        int i = idx / BS, o = idx - i*BS;
        float p_io = 0.5f*(w2a[idx] + w2b[idx]);
        float m_io = m_s[idx];
        float accK = 0.f, accN = 0.f;
        for (int j = 0; j < BS; ++j) {
            float p_ij = 0.5f*(w2a[i*BS + j] + w2b[i*BS + j]);
            float mjo  = m_s[j*BS + o];
            accK += p_ij * mjo;
            accN += m_s[i*BS + j] * mjo;
        }
        float valK = p_io + accK;
        float valN = p_io + m_io + accN;
        float wkp = 0.5f*(valK + valN);
        float wkm = 0.5f*(valK - valN);
        int d = n*BS*BS + o*BS + i;                // transposed [o][k=i]
        unsigned short hp = f2bf(wkp);
        WKPh[d] = hp;  WKPl[d] = f2bf(wkp - bf2f(hp));
        unsigned short hm = f2bf(wkm);
        WKMh[d] = hm;  WKMl[d] = f2bf(wkm - bf2f(hm));
    }
    if (tid < BS) {
        const float* b2a = b2 + (0*NB + n)*BS;
        const float* b2b = b2 + (1*NB + n)*BS;
        float acc = b2a[tid] + b2b[tid];
        for (int j = 0; j < BS; ++j) acc += b2a[j] * m_s[j*BS + tid];
        BEFF[n*BS + tid] = acc;
    }
}

// ---------------------------------------------------------------------------
// P1: forward W-axis via 256-pt Stockham FFT, channel-pair packing
// (unchanged from round 7).
// ---------------------------------------------------------------------------
__global__ __launch_bounds__(256) void k_p1(
    const float* __restrict__ x, float2* __restrict__ out)
{
    const int tid = threadIdx.x;
    const int row = blockIdx.y;           // 0..255 = b*HH+h
    const int c0 = blockIdx.x * 16;
    __shared__ float2 tw[256];
    __shared__ float2 bufA[8*256];        // 16 KB
    __shared__ float2 bufB[8*256];        // 16 KB

    {
        float sn, cs; sincosf(TWOPI*(float)tid/256.f, &sn, &cs);
        tw[tid] = make_float2(cs, -sn);
    }
    const float* xr = x + (size_t)row * WW * CC + c0;
    for (int idx = tid; idx < 2048; idx += 256) {
        int l = idx & 7, w = idx >> 3;
        const float2 v = *(const float2*)(xr + (size_t)w*CC + 2*l);
        bufA[l*256 + w] = v;
    }
    __syncthreads();

    float2* src = bufA;
    float2* dst = bufB;
    const int t  = tid & 127;
    const int l0 = tid >> 7;
    #pragma unroll
    for (int st = 0; st < 8; ++st) {
        const int s = 1 << st;
        const int q = t & (s - 1);
        const int p = t >> st;
        const float2 w = tw[p << st];
        #pragma unroll
        for (int k = 0; k < 4; ++k) {
            int base = (l0 + 2*k) * 256;
            float2 a = src[base + q + s*p];
            float2 b = src[base + q + s*p + 128];
            float dx = a.x - b.x, dy = a.y - b.y;
            dst[base + q + 2*s*p]     = make_float2(a.x + b.x, a.y + b.y);
            dst[base + q + 2*s*p + s] = make_float2(dx*w.x - dy*w.y, dx*w.y + dy*w.x);
        }
        __syncthreads();
        float2* tmp = src; src = dst; dst = tmp;
    }
    for (int idx = tid; idx < 8*WKEPT; idx += 256) {
        int l = idx & 7, wp = idx >> 3;
        float2 Z  = src[l*256 + wp];
        float2 Zm = src[l*256 + ((256 - wp) & 255)];
        float2 U = make_float2(0.5f*(Z.x + Zm.x), 0.5f*(Z.y - Zm.y));
        float2 V = make_float2(0.5f*(Z.y + Zm.y), 0.5f*(Zm.x - Z.x));
        size_t g = (size_t)(row*WKEPT + wp)*CC + c0 + 2*l;
        out[g]     = U;
        out[g + 1] = V;
    }
}

// ---------------------------------------------------------------------------
// P2/P6: C-axis 768-pt FFT per line (unchanged).
// ---------------------------------------------------------------------------
#define LPB 4
__global__ __launch_bounds__(256) void k_cfft(
    const float2* __restrict__ in, float2* __restrict__ out)
{
    __shared__ float2 tw[CC];
    __shared__ float2 bufA[LPB*CC];
    __shared__ float2 bufB[LPB*CC];
    const int tid = threadIdx.x;
    const size_t line0 = (size_t)blockIdx.x * LPB;

    for (int t = tid; t < CC; t += 256) {
        float sn, cs; sincosf(TWOPI * (float)t / 768.0f, &sn, &cs);
        tw[t] = make_float2(cs, -sn);
    }
    for (int idx = tid; idx < LPB*CC; idx += 256) {
        int l = idx / CC, c = idx - l*CC;
        int m = c / 3, j = c - 3*m;
        bufA[l*CC + j*256 + m] = in[(line0 + l)*CC + c];
    }
    __syncthreads();

    float2* src = bufA;
    float2* dst = bufB;
    #pragma unroll
    for (int st = 0; st < 8; ++st) {
        const int s = 1 << st;
        const int h = 128 >> st;
        for (int item = tid; item < LPB*3*128; item += 256) {
            int sub = item >> 7;
            int t   = item & 127;
            int q = t & (s - 1);
            int p = t >> st;
            float2 a = src[sub*256 + q + s*p];
            float2 b = src[sub*256 + q + s*(p + h)];
            float2 w = tw[p * (3 << st)];
            float dx = a.x - b.x, dy = a.y - b.y;
            dst[sub*256 + q + s*(2*p)]     = make_float2(a.x + b.x, a.y + b.y);
            dst[sub*256 + q + s*(2*p + 1)] = make_float2(dx*w.x - dy*w.y, dx*w.y + dy*w.x);
        }
        __syncthreads();
        float2* tmp = src; src = dst; dst = tmp;
    }
    for (int idx = tid; idx < LPB*CC; idx += 256) {
        int l = idx / CC, cp = idx - l*CC;
        int r = cp & 255;
        float2 S0 = src[(l*3 + 0)*256 + r];
        float2 S1 = src[(l*3 + 1)*256 + r];
        float2 S2 = src[(l*3 + 2)*256 + r];
        float2 w1 = tw[cp];
        int i2 = 2*cp; if (i2 >= CC) i2 -= CC;
        float2 w2 = tw[i2];
        float fr = S0.x + w1.x*S1.x - w1.y*S1.y + w2.x*S2.x - w2.y*S2.y;
        float fi = S0.y + w1.x*S1.y + w1.y*S1.x + w2.x*S2.y + w2.y*S2.x;
        out[(line0 + l)*CC + cp] = make_float2(fr, fi);
    }
}

// ---------------------------------------------------------------------------
// P3: H-axis via 128-pt radix-2 Stockham FFT (unchanged).
// ---------------------------------------------------------------------------
__global__ __launch_bounds__(256) void k_hb_c2a(
    const float2* __restrict__ in, float* __restrict__ aout)
{
    const int tid = threadIdx.x;
    const int wp = blockIdx.y;
    const int c0 = blockIdx.x * 8;
    __shared__ float2 tw[128];
    __shared__ float2 bufA[16*128];
    __shared__ float2 bufB[16*128];

    if (tid < 128) {
        float sn, cs; sincosf(TWOPI*(float)tid/128.f, &sn, &cs);
        tw[tid] = make_float2(cs, -sn);
    }
    for (int idx = tid; idx < 1024; idx += 256) {
        int cl = idx & 7, h = idx >> 3;
        float2 z0 = in[(size_t)((0*HH + h)*WKEPT + wp)*CC + c0 + cl];
        float2 z1 = in[(size_t)((1*HH + h)*WKEPT + wp)*CC + c0 + cl];
        bufA[(2*cl+0)*128 + h] = make_float2(z0.x+z1.x, z0.y+z1.y);
        bufA[(2*cl+1)*128 + h] = make_float2(z0.x-z1.x, z0.y-z1.y);
    }
    __syncthreads();

    float2* src = bufA;
    float2* dst = bufB;
    const int t  = tid & 63;
    const int l0 = tid >> 6;
    #pragma unroll
    for (int st = 0; st < 7; ++st) {
        const int s = 1 << st;
        const int q = t & (s - 1);
        const int p = t >> st;
        const float2 w = tw[p << st];
        #pragma unroll
        for (int k = 0; k < 4; ++k) {
            int base = (l0 + 4*k) * 128;
            float2 a = src[base + q + s*p];
            float2 b = src[base + q + s*p + 64];
            float dx = a.x - b.x, dy = a.y - b.y;
            dst[base + q + 2*s*p]     = make_float2(a.x + b.x, a.y + b.y);
            dst[base + q + 2*s*p + s] = make_float2(dx*w.x - dy*w.y, dx*w.y + dy*w.x);
        }
        __syncthreads();
        float2* tmp = src; src = dst; dst = tmp;
    }
    for (int idx = tid; idx < 2048; idx += 256) {
        int cl = idx & 7;
        int hp = (idx >> 3) & 127;
        int uv = idx >> 10;
        float2 z = src[(2*cl + uv)*128 + hp];
        aout[(size_t)((uv*HH + hp)*WKEPT + wp)*CC + c0 + cl] = z.x + z.y;
    }
}

// ---------------------------------------------------------------------------
// P5: H-axis FFT on REAL s via complex packing (unchanged).
// ---------------------------------------------------------------------------
__global__ __launch_bounds__(256) void k_hb_s2c(
    const float* __restrict__ sreal, float2* __restrict__ out)
{
    const int tid = threadIdx.x;
    const int wp = blockIdx.y;
    const int c0 = blockIdx.x * 16;
    __shared__ float2 tw[128];
    __shared__ float2 bufA[16*128];
    __shared__ float2 bufB[16*128];

    if (tid < 128) {
        float sn, cs; sincosf(TWOPI*(float)tid/128.f, &sn, &cs);
        tw[tid] = make_float2(cs, -sn);
    }
    for (int idx = tid; idx < 2048; idx += 256) {
        int cl = idx & 15, h = idx >> 4;
        float s0 = sreal[(size_t)((0*HH + h)*WKEPT + wp)*CC + c0 + cl];
        float s1 = sreal[(size_t)((1*HH + h)*WKEPT + wp)*CC + c0 + cl];
        bufA[cl*128 + h] = make_float2(s0 + s1, s0 - s1);   // z = u + i v
    }
    __syncthreads();

    float2* src = bufA;
    float2* dst = bufB;
    const int t  = tid & 63;
    const int l0 = tid >> 6;
    #pragma unroll
    for (int st = 0; st < 7; ++st) {
        const int s = 1 << st;
        const int q = t & (s - 1);
        const int p = t >> st;
        const float2 w = tw[p << st];
        #pragma unroll
        for (int k = 0; k < 4; ++k) {
            int base = (l0 + 4*k) * 128;
            float2 a = src[base + q + s*p];
            float2 b = src[base + q + s*p + 64];
            float dx = a.x - b.x, dy = a.y - b.y;
            dst[base + q + 2*s*p]     = make_float2(a.x + b.x, a.y + b.y);
            dst[base + q + 2*s*p + s] = make_float2(dx*w.x - dy*w.y, dx*w.y + dy*w.x);
        }
        __syncthreads();
        float2* tmp = src; src = dst; dst = tmp;
    }
    for (int idx = tid; idx < 2048; idx += 256) {
        int cl = idx & 15;
        int hp = idx >> 4;
        float2 A  = src[cl*128 + hp];
        float2 Zm = src[cl*128 + ((128 - hp) & 127)];
        float2 U = make_float2(0.5f*(A.x + Zm.x), 0.5f*(A.y - Zm.y));
        float2 V = make_float2(0.5f*(A.y + Zm.y), 0.5f*(Zm.x - A.x));
        out[(size_t)((0*HH + hp)*WKEPT + wp)*CC + c0 + cl] = U;
        out[(size_t)((1*HH + hp)*WKEPT + wp)*CC + c0 + cl] = V;
    }
}

// ---------------------------------------------------------------------------
// P4 (MFMA): fused MLP on matrix cores (unchanged from round 8).
// ---------------------------------------------------------------------------
__global__ __launch_bounds__(256, 2) void k_mlp(
    const float* __restrict__ a, const float* __restrict__ x,
    const unsigned short* __restrict__ W10h, const unsigned short* __restrict__ W10l,
    const unsigned short* __restrict__ W11h, const unsigned short* __restrict__ W11l,
    const unsigned short* __restrict__ WKPh, const unsigned short* __restrict__ WKPl,
    const unsigned short* __restrict__ WKMh, const unsigned short* __restrict__ WKMl,
    const float* __restrict__ b1, const float* __restrict__ BEFF,
    float* __restrict__ sout)
{
    const int tid = threadIdx.x;
    const int n = blockIdx.y;
    const int P0 = blockIdx.x * 64;
    __shared__ unsigned short Wh_A[96*48], Wl_A[96*48];
    __shared__ unsigned short Wh_B[96*48], Wl_B[96*48];
    __shared__ unsigned short PMp[64*104], PMm[64*104];

    const int lane = tid & 63;
    const int wv = tid >> 6;
    const int lr = lane & 15;
    const int lk = lane >> 4;

    const int Pld = P0 + 16*wv + lr;
    int bb = Pld / (HH*WKEPT);
    int rem = Pld - bb*(HH*WKEPT);
    int h = rem / WKEPT;
    int wq = rem - h*WKEPT;
    int hh2 = (HH - h) & (HH-1);
    int ww2 = (WW - wq) & (WW-1);
    const float* aRow  = a + (size_t)Pld*CC + n*BS;
    const float* anRow = x + (size_t)((bb*HH + hh2)*WW + ww2)*CC + n*BS;

    f32x4 T1[6], T2[6];
    #pragma unroll
    for (int t = 0; t < 6; ++t) {
        T1[t] = (f32x4){0.f,0.f,0.f,0.f};
        T2[t] = (f32x4){0.f,0.f,0.f,0.f};
    }

    for (int ks = 0; ks < 3; ++ks) {
        __syncthreads();
        for (int idx = tid; idx < 96*16; idx += 256) {
            int o = idx >> 4, kp = (idx & 15) << 1;
            int g = n*BS*BS + o*BS + ks*32 + kp;
            *(ushort2*)&Wh_A[o*48 + kp] = *(const ushort2*)&W10h[g];
            *(ushort2*)&Wl_A[o*48 + kp] = *(const ushort2*)&W10l[g];
            *(ushort2*)&Wh_B[o*48 + kp] = *(const ushort2*)&W11h[g];
            *(ushort2*)&Wl_B[o*48 + kp] = *(const ushort2*)&W11l[g];
        }
        __syncthreads();

        const int kseg = ks*32 + 8*lk;
        float4 a0 = *(const float4*)(aRow + kseg);
        float4 a1 = *(const float4*)(aRow + kseg + 4);
        float4 n0 = *(const float4*)(anRow + kseg);
        float4 n1 = *(const float4*)(anRow + kseg + 4);
        bf16x8 uF, vF;
        uF[0] = (short)f2bf(0.5f*(a0.x + n0.x));  vF[0] = (short)f2bf(0.5f*(a0.x - n0.x));
        uF[1] = (short)f2bf(0.5f*(a0.y + n0.y));  vF[1] = (short)f2bf(0.5f*(a0.y - n0.y));
        uF[2] = (short)f2bf(0.5f*(a0.z + n0.z));  vF[2] = (short)f2bf(0.5f*(a0.z - n0.z));
        uF[3] = (short)f2bf(0.5f*(a0.w + n0.w));  vF[3] = (short)f2bf(0.5f*(a0.w - n0.w));
        uF[4] = (short)f2bf(0.5f*(a1.x + n1.x));  vF[4] = (short)f2bf(0.5f*(a1.x - n1.x));
        uF[5] = (short)f2bf(0.5f*(a1.y + n1.y));  vF[5] = (short)f2bf(0.5f*(a1.y - n1.y));
        uF[6] = (short)f2bf(0.5f*(a1.z + n1.z));  vF[6] = (short)f2bf(0.5f*(a1.z - n1.z));
        uF[7] = (short)f2bf(0.5f*(a1.w + n1.w));  vF[7] = (short)f2bf(0.5f*(a1.w - n1.w));

        #pragma unroll
        for (int t = 0; t < 6; ++t) {
            int wb = (16*t + lr)*48 + 8*lk;
            bf16x8 bh = *(const bf16x8*)&Wh_A[wb];
            T1[t] = __builtin_amdgcn_mfma_f32_16x16x32_bf16(uF, bh, T1[t], 0, 0, 0);
            bf16x8 bl = *(const bf16x8*)&Wl_A[wb];
            T1[t] = __builtin_amdgcn_mfma_f32_16x16x32_bf16(uF, bl, T1[t], 0, 0, 0);
            bf16x8 ch = *(const bf16x8*)&Wh_B[wb];
            T2[t] = __builtin_amdgcn_mfma_f32_16x16x32_bf16(vF, ch, T2[t], 0, 0, 0);
            bf16x8 cl = *(const bf16x8*)&Wl_B[wb];
            T2[t] = __builtin_amdgcn_mfma_f32_16x16x32_bf16(vF, cl, T2[t], 0, 0, 0);
        }
    }

    #pragma unroll
    for (int t = 0; t < 6; ++t) {
        float bk = b1[(0*NB + n)*BS + 16*t + lr];
        float bn = b1[(1*NB + n)*BS + 16*t + lr];
        #pragma unroll
        for (int r = 0; r < 4; ++r) {
            float ok = fmaxf(T1[t][r] + T2[t][r] + bk, 0.f);
            float on = fmaxf(T1[t][r] - T2[t][r] + bn, 0.f);
            int pl = 16*wv + 4*lk + r;
            PMp[pl*104 + 16*t + lr] = f2bf(ok + on);
            PMm[pl*104 + 16*t + lr] = f2bf(ok - on);
        }
    }

    f32x4 S[6];
    #pragma unroll
    for (int t = 0; t < 6; ++t) S[t] = (f32x4){0.f,0.f,0.f,0.f};
    for (int ks = 0; ks < 3; ++ks) {
        __syncthreads();
        for (int idx = tid; idx < 96*16; idx += 256) {
            int o = idx >> 4, kp = (idx & 15) << 1;
            int g = n*BS*BS + o*BS + ks*32 + kp;
            *(ushort2*)&Wh_A[o*48 + kp] = *(const ushort2*)&WKPh[g];
            *(ushort2*)&Wl_A[o*48 + kp] = *(const ushort2*)&WKPl[g];
            *(ushort2*)&Wh_B[o*48 + kp] = *(const ushort2*)&WKMh[g];
            *(ushort2*)&Wl_B[o*48 + kp] = *(const ushort2*)&WKMl[g];
        }
        __syncthreads();

        const int kseg = ks*32 + 8*lk;
        bf16x8 pF = *(const bf16x8*)&PMp[(16*wv + lr)*104 + kseg];
        bf16x8 mF = *(const bf16x8*)&PMm[(16*wv + lr)*104 + kseg];
        #pragma unroll
        for (int t = 0; t < 6; ++t) {
            int wb = (16*t + lr)*48 + 8*lk;
            bf16x8 bh = *(const bf16x8*)&Wh_A[wb];
            S[t] = __builtin_amdgcn_mfma_f32_16x16x32_bf16(pF, bh, S[t], 0, 0, 0);
            bf16x8 bl = *(const bf16x8*)&Wl_A[wb];
            S[t] = __builtin_amdgcn_mfma_f32_16x16x32_bf16(pF, bl, S[t], 0, 0, 0);
            bf16x8 ch = *(const bf16x8*)&Wh_B[wb];
            S[t] = __builtin_amdgcn_mfma_f32_16x16x32_bf16(mF, ch, S[t], 0, 0, 0);
            bf16x8 cl = *(const bf16x8*)&Wl_B[wb];
            S[t] = __builtin_amdgcn_mfma_f32_16x16x32_bf16(mF, cl, S[t], 0, 0, 0);
        }
    }

    #pragma unroll
    for (int t = 0; t < 6; ++t) {
        float be = BEFF[n*BS + 16*t + lr];
        #pragma unroll
        for (int r = 0; r < 4; ++r) {
            float v = S[t][r] + be;
            float av2 = fabsf(v) - 0.01f;
            float sv = (av2 > 0.f) ? copysignf(av2, v) : 0.f;
            int pt = P0 + 16*wv + 4*lk + r;
            sout[(size_t)pt*CC + n*BS + 16*t + lr] = sv;
        }
    }
}

// ---------------------------------------------------------------------------
// P7 (v2): inverse W expansion via 256-pt Stockham FFT, zero-padded spectrum.
// Per block: 8 channels of one row; A read EXACTLY ONCE (was 16x re-read).
// out[w] = Re(Z)+Im(Z), Z = forward FFT of padded A — verified algebraically
// identical to the old direct form (z.x+z.y = P*cos + M*sin). Same recurrence
// and twiddle convention as verified k_p1. No twiddle tables needed.
// LDS 34.3 KB -> 4 blocks/CU. grid (96, 256), 256 thr.
// ---------------------------------------------------------------------------
__global__ __launch_bounds__(256) void k_p7(
    const float2* __restrict__ A, const float* __restrict__ x,
    float* __restrict__ out)
{
    const int tid = threadIdx.x;
    const int row = blockIdx.y;           // 0..255 = b*HH+h
    const int c0 = blockIdx.x * 8;
    __shared__ float2 tw[256];
    __shared__ float2 bufA[8*256];        // 16 KB
    __shared__ float2 bufB[8*256];        // 16 KB

    {
        float sn, cs; sincosf(TWOPI*(float)tid/256.f, &sn, &cs);
        tw[tid] = make_float2(cs, -sn);
    }
    // load kept spectrum, zero-pad wq >= 65
    const float2* Ar = A + (size_t)row * WKEPT * CC + c0;
    for (int idx = tid; idx < 2048; idx += 256) {
        int l = idx & 7, w = idx >> 3;
        bufA[l*256 + w] = (w < WKEPT) ? Ar[(size_t)w*CC + l]
                                      : make_float2(0.f, 0.f);
    }
    __syncthreads();

    float2* src = bufA;
    float2* dst = bufB;
    const int t  = tid & 127;
    const int l0 = tid >> 7;
    #pragma unroll
    for (int st = 0; st < 8; ++st) {
        const int s = 1 << st;
        const int q = t & (s - 1);
        const int p = t >> st;
        const float2 w = tw[p << st];
        #pragma unroll
        for (int k = 0; k < 4; ++k) {
            int base = (l0 + 2*k) * 256;
            float2 a = src[base + q + s*p];
            float2 b = src[base + q + s*p + 128];
            float dx = a.x - b.x, dy = a.y - b.y;
            dst[base + q + 2*s*p]     = make_float2(a.x + b.x, a.y + b.y);
            dst[base + q + 2*s*p + s] = make_float2(dx*w.x - dy*w.y, dx*w.y + dy*w.x);
        }
        __syncthreads();
        float2* tmp = src; src = dst; dst = tmp;
    }
    // 8 swaps -> result back in bufA (== src). out = (Re+Im)*scale + x
    const float scale = 1.0f / 50331648.0f;
    const size_t obase = (size_t)row * WW * CC + c0;
    for (int idx = tid; idx < 2048; idx += 256) {
        int l = idx & 7, w = idx >> 3;
        float2 z = src[l*256 + w];
        size_t g = obase + (size_t)w*CC + l;
        out[g] = fmaf(z.x + z.y, scale, x[g]);
    }
}

// ---------------------------------------------------------------------------
// Launch. ws layout:
//   floats: Abuf (2*NPTS*CC, halves double as a_real/s_real) | BEFF
//   then ushorts: W10h,W10l,W11h,W11l,WKPh,WKPl,WKMh,WKMl (each NB*96*96)
// d_out doubles as complex buffer B.
// ---------------------------------------------------------------------------
extern "C" void kernel_launch(void* const* d_in, const int* in_sizes, int n_in,
                              void* d_out, int out_size, void* d_ws, size_t ws_size,
                              hipStream_t stream)
{
    (void)in_sizes; (void)n_in; (void)out_size; (void)ws_size;
    const float* x  = (const float*)d_in[0];
    const float* w1 = (const float*)d_in[1];
    const float* b1 = (const float*)d_in[2];
    const float* w2 = (const float*)d_in[3];
    const float* b2 = (const float*)d_in[4];

    float*  ws     = (float*)d_ws;
    float2* Abuf   = (float2*)d_ws;
    float*  a_real = ws;
    float*  s_real = ws + (size_t)NPTS*CC;
    float*  BEFF   = ws + 2*(size_t)NPTS*CC;
    unsigned short* Wq = (unsigned short*)(BEFF + NB*BS);
    const size_t WSZ = (size_t)NB*BS*BS;
    unsigned short* W10h = Wq + 0*WSZ;
    unsigned short* W10l = Wq + 1*WSZ;
    unsigned short* W11h = Wq + 2*WSZ;
    unsigned short* W11l = Wq + 3*WSZ;
    unsigned short* WKPh = Wq + 4*WSZ;
    unsigned short* WKPl = Wq + 5*WSZ;
    unsigned short* WKMh = Wq + 6*WSZ;
    unsigned short* WKMl = Wq + 7*WSZ;

    float2* Bc   = (float2*)d_out;
    float*  outf = (float*)d_out;

    k_weights<<<dim3(NB), dim3(256), 0, stream>>>(
        w1, w2, b2, W10h, W10l, W11h, W11l, WKPh, WKPl, WKMh, WKMl, BEFF);
    k_p1     <<<dim3(48, 256), dim3(256), 0, stream>>>(x, Abuf);
    k_cfft   <<<dim3(NPTS/LPB), dim3(256), 0, stream>>>(Abuf, Bc);
    k_hb_c2a <<<dim3(96, WKEPT), dim3(256), 0, stream>>>(Bc, a_real);
    k_mlp    <<<dim3(260, NB), dim3(256), 0, stream>>>(
        a_real, x, W10h, W10l, W11h, W11l, WKPh, WKPl, WKMh, WKMl,
        b1, BEFF, s_real);
    k_hb_s2c <<<dim3(48, WKEPT), dim3(256), 0, stream>>>(s_real, Bc);
    k_cfft   <<<dim3(NPTS/LPB), dim3(256), 0, stream>>>(Bc, Abuf);
    k_p7     <<<dim3(96, 256), dim3(256), 0, stream>>>(Abuf, x, outf);
}

// Round 10
// 1022.936 us; speedup vs baseline: 1.1200x; 1.1200x over previous
//
#include <hip/hip_runtime.h>

#define BB 2
#define HH 128
#define WW 256
#define CC 768
#define NB 8
#define BS 96
#define WKEPT 65
#define NPTS (BB*HH*WKEPT)        // 16640 kept (b,h,w') points
#define NTOT ((size_t)BB*HH*WW*CC) // 50331648
#define TWOPI 6.283185307179586f

typedef __attribute__((ext_vector_type(8))) short bf16x8;
typedef __attribute__((ext_vector_type(4))) float f32x4;

__device__ __forceinline__ unsigned short f2bf(float f) {
    unsigned int u = __float_as_uint(f);
    u += 0x7fffu + ((u >> 16) & 1u);      // round-to-nearest-even
    return (unsigned short)(u >> 16);
}
__device__ __forceinline__ float bf2f(unsigned short s) {
    return __uint_as_float((unsigned int)s << 16);
}

// ---------------------------------------------------------------------------
// K0: precombine weights into TRANSPOSED bf16 hi/lo pairs for MFMA
// (unchanged from round 8).
// ---------------------------------------------------------------------------
__global__ __launch_bounds__(256) void k_weights(
    const float* __restrict__ w1, const float* __restrict__ w2,
    const float* __restrict__ b2,
    unsigned short* __restrict__ W10h, unsigned short* __restrict__ W10l,
    unsigned short* __restrict__ W11h, unsigned short* __restrict__ W11l,
    unsigned short* __restrict__ WKPh, unsigned short* __restrict__ WKPl,
    unsigned short* __restrict__ WKMh, unsigned short* __restrict__ WKMl,
    float* __restrict__ BEFF)
{
    const int n = blockIdx.x;
    const int tid = threadIdx.x;
    __shared__ float m_s[BS*BS];

    const float* w2a = w2 + (size_t)(0*NB + n)*BS*BS;
    const float* w2b = w2 + (size_t)(1*NB + n)*BS*BS;
    for (int idx = tid; idx < BS*BS; idx += 256)
        m_s[idx] = 0.5f*(w2a[idx] - w2b[idx]);

    const float* w1a = w1 + (size_t)(0*NB + n)*BS*BS;
    const float* w1b = w1 + (size_t)(1*NB + n)*BS*BS;
    for (int idx = tid; idx < BS*BS; idx += 256) {
        int o = idx / BS, k = idx - o*BS;          // dest [o][k]
        float v0 = w1a[k*BS + o];
        unsigned short h0 = f2bf(v0);
        unsigned short l0 = f2bf(v0 - bf2f(h0));
        W10h[n*BS*BS + idx] = h0;  W10l[n*BS*BS + idx] = l0;
        float v1 = w1b[k*BS + o];
        unsigned short h1 = f2bf(v1);
        unsigned short l1 = f2bf(v1 - bf2f(h1));
        W11h[n*BS*BS + idx] = h1;  W11l[n*BS*BS + idx] = l1;
    }
    __syncthreads();

    for (int idx = tid; idx < BS*BS; idx += 256) {
        int i = idx / BS, o = idx - i*BS;
        float p_io = 0.5f*(w2a[idx] + w2b[idx]);
        float m_io = m_s[idx];
        float accK = 0.f, accN = 0.f;
        for (int j = 0; j < BS; ++j) {
            float p_ij = 0.5f*(w2a[i*BS + j] + w2b[i*BS + j]);
            float mjo  = m_s[j*BS + o];
            accK += p_ij * mjo;
            accN += m_s[i*BS + j] * mjo;
        }
        float valK = p_io + accK;
        float valN = p_io + m_io + accN;
        float wkp = 0.5f*(valK + valN);
        float wkm = 0.5f*(valK - valN);
        int d = n*BS*BS + o*BS + i;                // transposed [o][k=i]
        unsigned short hp = f2bf(wkp);
        WKPh[d] = hp;  WKPl[d] = f2bf(wkp - bf2f(hp));
        unsigned short hm = f2bf(wkm);
        WKMh[d] = hm;  WKMl[d] = f2bf(wkm - bf2f(hm));
    }
    if (tid < BS) {
        const float* b2a = b2 + (0*NB + n)*BS;
        const float* b2b = b2 + (1*NB + n)*BS;
        float acc = b2a[tid] + b2b[tid];
        for (int j = 0; j < BS; ++j) acc += b2a[j] * m_s[j*BS + tid];
        BEFF[n*BS + tid] = acc;
    }
}

// ---------------------------------------------------------------------------
// P1: forward W-axis via 256-pt Stockham FFT, channel-pair packing
// (unchanged from round 7).
// ---------------------------------------------------------------------------
__global__ __launch_bounds__(256) void k_p1(
    const float* __restrict__ x, float2* __restrict__ out)
{
    const int tid = threadIdx.x;
    const int row = blockIdx.y;           // 0..255 = b*HH+h
    const int c0 = blockIdx.x * 16;
    __shared__ float2 tw[256];
    __shared__ float2 bufA[8*256];        // 16 KB
    __shared__ float2 bufB[8*256];        // 16 KB

    {
        float sn, cs; sincosf(TWOPI*(float)tid/256.f, &sn, &cs);
        tw[tid] = make_float2(cs, -sn);
    }
    const float* xr = x + (size_t)row * WW * CC + c0;
    for (int idx = tid; idx < 2048; idx += 256) {
        int l = idx & 7, w = idx >> 3;
        const float2 v = *(const float2*)(xr + (size_t)w*CC + 2*l);
        bufA[l*256 + w] = v;
    }
    __syncthreads();

    float2* src = bufA;
    float2* dst = bufB;
    const int t  = tid & 127;
    const int l0 = tid >> 7;
    #pragma unroll
    for (int st = 0; st < 8; ++st) {
        const int s = 1 << st;
        const int q = t & (s - 1);
        const int p = t >> st;
        const float2 w = tw[p << st];
        #pragma unroll
        for (int k = 0; k < 4; ++k) {
            int base = (l0 + 2*k) * 256;
            float2 a = src[base + q + s*p];
            float2 b = src[base + q + s*p + 128];
            float dx = a.x - b.x, dy = a.y - b.y;
            dst[base + q + 2*s*p]     = make_float2(a.x + b.x, a.y + b.y);
            dst[base + q + 2*s*p + s] = make_float2(dx*w.x - dy*w.y, dx*w.y + dy*w.x);
        }
        __syncthreads();
        float2* tmp = src; src = dst; dst = tmp;
    }
    for (int idx = tid; idx < 8*WKEPT; idx += 256) {
        int l = idx & 7, wp = idx >> 3;
        float2 Z  = src[l*256 + wp];
        float2 Zm = src[l*256 + ((256 - wp) & 255)];
        float2 U = make_float2(0.5f*(Z.x + Zm.x), 0.5f*(Z.y - Zm.y));
        float2 V = make_float2(0.5f*(Z.y + Zm.y), 0.5f*(Zm.x - Z.x));
        size_t g = (size_t)(row*WKEPT + wp)*CC + c0 + 2*l;
        out[g]     = U;
        out[g + 1] = V;
    }
}

// ---------------------------------------------------------------------------
// P2/P6: C-axis 768-pt FFT per line (unchanged).
// ---------------------------------------------------------------------------
#define LPB 4
__global__ __launch_bounds__(256) void k_cfft(
    const float2* __restrict__ in, float2* __restrict__ out)
{
    __shared__ float2 tw[CC];
    __shared__ float2 bufA[LPB*CC];
    __shared__ float2 bufB[LPB*CC];
    const int tid = threadIdx.x;
    const size_t line0 = (size_t)blockIdx.x * LPB;

    for (int t = tid; t < CC; t += 256) {
        float sn, cs; sincosf(TWOPI * (float)t / 768.0f, &sn, &cs);
        tw[t] = make_float2(cs, -sn);
    }
    for (int idx = tid; idx < LPB*CC; idx += 256) {
        int l = idx / CC, c = idx - l*CC;
        int m = c / 3, j = c - 3*m;
        bufA[l*CC + j*256 + m] = in[(line0 + l)*CC + c];
    }
    __syncthreads();

    float2* src = bufA;
    float2* dst = bufB;
    #pragma unroll
    for (int st = 0; st < 8; ++st) {
        const int s = 1 << st;
        const int h = 128 >> st;
        for (int item = tid; item < LPB*3*128; item += 256) {
            int sub = item >> 7;
            int t   = item & 127;
            int q = t & (s - 1);
            int p = t >> st;
            float2 a = src[sub*256 + q + s*p];
            float2 b = src[sub*256 + q + s*(p + h)];
            float2 w = tw[p * (3 << st)];
            float dx = a.x - b.x, dy = a.y - b.y;
            dst[sub*256 + q + s*(2*p)]     = make_float2(a.x + b.x, a.y + b.y);
            dst[sub*256 + q + s*(2*p + 1)] = make_float2(dx*w.x - dy*w.y, dx*w.y + dy*w.x);
        }
        __syncthreads();
        float2* tmp = src; src = dst; dst = tmp;
    }
    for (int idx = tid; idx < LPB*CC; idx += 256) {
        int l = idx / CC, cp = idx - l*CC;
        int r = cp & 255;
        float2 S0 = src[(l*3 + 0)*256 + r];
        float2 S1 = src[(l*3 + 1)*256 + r];
        float2 S2 = src[(l*3 + 2)*256 + r];
        float2 w1 = tw[cp];
        int i2 = 2*cp; if (i2 >= CC) i2 -= CC;
        float2 w2 = tw[i2];
        float fr = S0.x + w1.x*S1.x - w1.y*S1.y + w2.x*S2.x - w2.y*S2.y;
        float fi = S0.y + w1.x*S1.y + w1.y*S1.x + w2.x*S2.y + w2.y*S2.x;
        out[(line0 + l)*CC + cp] = make_float2(fr, fi);
    }
}

// ---------------------------------------------------------------------------
// P3: H-axis via 128-pt radix-2 Stockham FFT (unchanged).
// ---------------------------------------------------------------------------
__global__ __launch_bounds__(256) void k_hb_c2a(
    const float2* __restrict__ in, float* __restrict__ aout)
{
    const int tid = threadIdx.x;
    const int wp = blockIdx.y;
    const int c0 = blockIdx.x * 8;
    __shared__ float2 tw[128];
    __shared__ float2 bufA[16*128];
    __shared__ float2 bufB[16*128];

    if (tid < 128) {
        float sn, cs; sincosf(TWOPI*(float)tid/128.f, &sn, &cs);
        tw[tid] = make_float2(cs, -sn);
    }
    for (int idx = tid; idx < 1024; idx += 256) {
        int cl = idx & 7, h = idx >> 3;
        float2 z0 = in[(size_t)((0*HH + h)*WKEPT + wp)*CC + c0 + cl];
        float2 z1 = in[(size_t)((1*HH + h)*WKEPT + wp)*CC + c0 + cl];
        bufA[(2*cl+0)*128 + h] = make_float2(z0.x+z1.x, z0.y+z1.y);
        bufA[(2*cl+1)*128 + h] = make_float2(z0.x-z1.x, z0.y-z1.y);
    }
    __syncthreads();

    float2* src = bufA;
    float2* dst = bufB;
    const int t  = tid & 63;
    const int l0 = tid >> 6;
    #pragma unroll
    for (int st = 0; st < 7; ++st) {
        const int s = 1 << st;
        const int q = t & (s - 1);
        const int p = t >> st;
        const float2 w = tw[p << st];
        #pragma unroll
        for (int k = 0; k < 4; ++k) {
            int base = (l0 + 4*k) * 128;
            float2 a = src[base + q + s*p];
            float2 b = src[base + q + s*p + 64];
            float dx = a.x - b.x, dy = a.y - b.y;
            dst[base + q + 2*s*p]     = make_float2(a.x + b.x, a.y + b.y);
            dst[base + q + 2*s*p + s] = make_float2(dx*w.x - dy*w.y, dx*w.y + dy*w.x);
        }
        __syncthreads();
        float2* tmp = src; src = dst; dst = tmp;
    }
    for (int idx = tid; idx < 2048; idx += 256) {
        int cl = idx & 7;
        int hp = (idx >> 3) & 127;
        int uv = idx >> 10;
        float2 z = src[(2*cl + uv)*128 + hp];
        aout[(size_t)((uv*HH + hp)*WKEPT + wp)*CC + c0 + cl] = z.x + z.y;
    }
}

// ---------------------------------------------------------------------------
// P5: H-axis FFT on REAL s via complex packing (unchanged).
// ---------------------------------------------------------------------------
__global__ __launch_bounds__(256) void k_hb_s2c(
    const float* __restrict__ sreal, float2* __restrict__ out)
{
    const int tid = threadIdx.x;
    const int wp = blockIdx.y;
    const int c0 = blockIdx.x * 16;
    __shared__ float2 tw[128];
    __shared__ float2 bufA[16*128];
    __shared__ float2 bufB[16*128];

    if (tid < 128) {
        float sn, cs; sincosf(TWOPI*(float)tid/128.f, &sn, &cs);
        tw[tid] = make_float2(cs, -sn);
    }
    for (int idx = tid; idx < 2048; idx += 256) {
        int cl = idx & 15, h = idx >> 4;
        float s0 = sreal[(size_t)((0*HH + h)*WKEPT + wp)*CC + c0 + cl];
        float s1 = sreal[(size_t)((1*HH + h)*WKEPT + wp)*CC + c0 + cl];
        bufA[cl*128 + h] = make_float2(s0 + s1, s0 - s1);   // z = u + i v
    }
    __syncthreads();

    float2* src = bufA;
    float2* dst = bufB;
    const int t  = tid & 63;
    const int l0 = tid >> 6;
    #pragma unroll
    for (int st = 0; st < 7; ++st) {
        const int s = 1 << st;
        const int q = t & (s - 1);
        const int p = t >> st;
        const float2 w = tw[p << st];
        #pragma unroll
        for (int k = 0; k < 4; ++k) {
            int base = (l0 + 4*k) * 128;
            float2 a = src[base + q + s*p];
            float2 b = src[base + q + s*p + 64];
            float dx = a.x - b.x, dy = a.y - b.y;
            dst[base + q + 2*s*p]     = make_float2(a.x + b.x, a.y + b.y);
            dst[base + q + 2*s*p + s] = make_float2(dx*w.x - dy*w.y, dx*w.y + dy*w.x);
        }
        __syncthreads();
        float2* tmp = src; src = dst; dst = tmp;
    }
    for (int idx = tid; idx < 2048; idx += 256) {
        int cl = idx & 15;
        int hp = idx >> 4;
        float2 A  = src[cl*128 + hp];
        float2 Zm = src[cl*128 + ((128 - hp) & 127)];
        float2 U = make_float2(0.5f*(A.x + Zm.x), 0.5f*(A.y - Zm.y));
        float2 V = make_float2(0.5f*(A.y + Zm.y), 0.5f*(Zm.x - A.x));
        out[(size_t)((0*HH + hp)*WKEPT + wp)*CC + c0 + cl] = U;
        out[(size_t)((1*HH + hp)*WKEPT + wp)*CC + c0 + cl] = V;
    }
}

// ---------------------------------------------------------------------------
// P4 (MFMA): fused MLP on matrix cores (unchanged from round 8).
// ---------------------------------------------------------------------------
__global__ __launch_bounds__(256, 2) void k_mlp(
    const float* __restrict__ a, const float* __restrict__ x,
    const unsigned short* __restrict__ W10h, const unsigned short* __restrict__ W10l,
    const unsigned short* __restrict__ W11h, const unsigned short* __restrict__ W11l,
    const unsigned short* __restrict__ WKPh, const unsigned short* __restrict__ WKPl,
    const unsigned short* __restrict__ WKMh, const unsigned short* __restrict__ WKMl,
    const float* __restrict__ b1, const float* __restrict__ BEFF,
    float* __restrict__ sout)
{
    const int tid = threadIdx.x;
    const int n = blockIdx.y;
    const int P0 = blockIdx.x * 64;
    __shared__ unsigned short Wh_A[96*48], Wl_A[96*48];
    __shared__ unsigned short Wh_B[96*48], Wl_B[96*48];
    __shared__ unsigned short PMp[64*104], PMm[64*104];

    const int lane = tid & 63;
    const int wv = tid >> 6;
    const int lr = lane & 15;
    const int lk = lane >> 4;

    const int Pld = P0 + 16*wv + lr;
    int bb = Pld / (HH*WKEPT);
    int rem = Pld - bb*(HH*WKEPT);
    int h = rem / WKEPT;
    int wq = rem - h*WKEPT;
    int hh2 = (HH - h) & (HH-1);
    int ww2 = (WW - wq) & (WW-1);
    const float* aRow  = a + (size_t)Pld*CC + n*BS;
    const float* anRow = x + (size_t)((bb*HH + hh2)*WW + ww2)*CC + n*BS;

    f32x4 T1[6], T2[6];
    #pragma unroll
    for (int t = 0; t < 6; ++t) {
        T1[t] = (f32x4){0.f,0.f,0.f,0.f};
        T2[t] = (f32x4){0.f,0.f,0.f,0.f};
    }

    for (int ks = 0; ks < 3; ++ks) {
        __syncthreads();
        for (int idx = tid; idx < 96*16; idx += 256) {
            int o = idx >> 4, kp = (idx & 15) << 1;
            int g = n*BS*BS + o*BS + ks*32 + kp;
            *(ushort2*)&Wh_A[o*48 + kp] = *(const ushort2*)&W10h[g];
            *(ushort2*)&Wl_A[o*48 + kp] = *(const ushort2*)&W10l[g];
            *(ushort2*)&Wh_B[o*48 + kp] = *(const ushort2*)&W11h[g];
            *(ushort2*)&Wl_B[o*48 + kp] = *(const ushort2*)&W11l[g];
        }
        __syncthreads();

        const int kseg = ks*32 + 8*lk;
        float4 a0 = *(const float4*)(aRow + kseg);
        float4 a1 = *(const float4*)(aRow + kseg + 4);
        float4 n0 = *(const float4*)(anRow + kseg);
        float4 n1 = *(const float4*)(anRow + kseg + 4);
        bf16x8 uF, vF;
        uF[0] = (short)f2bf(0.5f*(a0.x + n0.x));  vF[0] = (short)f2bf(0.5f*(a0.x - n0.x));
        uF[1] = (short)f2bf(0.5f*(a0.y + n0.y));  vF[1] = (short)f2bf(0.5f*(a0.y - n0.y));
        uF[2] = (short)f2bf(0.5f*(a0.z + n0.z));  vF[2] = (short)f2bf(0.5f*(a0.z - n0.z));
        uF[3] = (short)f2bf(0.5f*(a0.w + n0.w));  vF[3] = (short)f2bf(0.5f*(a0.w - n0.w));
        uF[4] = (short)f2bf(0.5f*(a1.x + n1.x));  vF[4] = (short)f2bf(0.5f*(a1.x - n1.x));
        uF[5] = (short)f2bf(0.5f*(a1.y + n1.y));  vF[5] = (short)f2bf(0.5f*(a1.y - n1.y));
        uF[6] = (short)f2bf(0.5f*(a1.z + n1.z));  vF[6] = (short)f2bf(0.5f*(a1.z - n1.z));
        uF[7] = (short)f2bf(0.5f*(a1.w + n1.w));  vF[7] = (short)f2bf(0.5f*(a1.w - n1.w));

        #pragma unroll
        for (int t = 0; t < 6; ++t) {
            int wb = (16*t + lr)*48 + 8*lk;
            bf16x8 bh = *(const bf16x8*)&Wh_A[wb];
            T1[t] = __builtin_amdgcn_mfma_f32_16x16x32_bf16(uF, bh, T1[t], 0, 0, 0);
            bf16x8 bl = *(const bf16x8*)&Wl_A[wb];
            T1[t] = __builtin_amdgcn_mfma_f32_16x16x32_bf16(uF, bl, T1[t], 0, 0, 0);
            bf16x8 ch = *(const bf16x8*)&Wh_B[wb];
            T2[t] = __builtin_amdgcn_mfma_f32_16x16x32_bf16(vF, ch, T2[t], 0, 0, 0);
            bf16x8 cl = *(const bf16x8*)&Wl_B[wb];
            T2[t] = __builtin_amdgcn_mfma_f32_16x16x32_bf16(vF, cl, T2[t], 0, 0, 0);
        }
    }

    #pragma unroll
    for (int t = 0; t < 6; ++t) {
        float bk = b1[(0*NB + n)*BS + 16*t + lr];
        float bn = b1[(1*NB + n)*BS + 16*t + lr];
        #pragma unroll
        for (int r = 0; r < 4; ++r) {
            float ok = fmaxf(T1[t][r] + T2[t][r] + bk, 0.f);
            float on = fmaxf(T1[t][r] - T2[t][r] + bn, 0.f);
            int pl = 16*wv + 4*lk + r;
            PMp[pl*104 + 16*t + lr] = f2bf(ok + on);
            PMm[pl*104 + 16*t + lr] = f2bf(ok - on);
        }
    }

    f32x4 S[6];
    #pragma unroll
    for (int t = 0; t < 6; ++t) S[t] = (f32x4){0.f,0.f,0.f,0.f};
    for (int ks = 0; ks < 3; ++ks) {
        __syncthreads();
        for (int idx = tid; idx < 96*16; idx += 256) {
            int o = idx >> 4, kp = (idx & 15) << 1;
            int g = n*BS*BS + o*BS + ks*32 + kp;
            *(ushort2*)&Wh_A[o*48 + kp] = *(const ushort2*)&WKPh[g];
            *(ushort2*)&Wl_A[o*48 + kp] = *(const ushort2*)&WKPl[g];
            *(ushort2*)&Wh_B[o*48 + kp] = *(const ushort2*)&WKMh[g];
            *(ushort2*)&Wl_B[o*48 + kp] = *(const ushort2*)&WKMl[g];
        }
        __syncthreads();

        const int kseg = ks*32 + 8*lk;
        bf16x8 pF = *(const bf16x8*)&PMp[(16*wv + lr)*104 + kseg];
        bf16x8 mF = *(const bf16x8*)&PMm[(16*wv + lr)*104 + kseg];
        #pragma unroll
        for (int t = 0; t < 6; ++t) {
            int wb = (16*t + lr)*48 + 8*lk;
            bf16x8 bh = *(const bf16x8*)&Wh_A[wb];
            S[t] = __builtin_amdgcn_mfma_f32_16x16x32_bf16(pF, bh, S[t], 0, 0, 0);
            bf16x8 bl = *(const bf16x8*)&Wl_A[wb];
            S[t] = __builtin_amdgcn_mfma_f32_16x16x32_bf16(pF, bl, S[t], 0, 0, 0);
            bf16x8 ch = *(const bf16x8*)&Wh_B[wb];
            S[t] = __builtin_amdgcn_mfma_f32_16x16x32_bf16(mF, ch, S[t], 0, 0, 0);
            bf16x8 cl = *(const bf16x8*)&Wl_B[wb];
            S[t] = __builtin_amdgcn_mfma_f32_16x16x32_bf16(mF, cl, S[t], 0, 0, 0);
        }
    }

    #pragma unroll
    for (int t = 0; t < 6; ++t) {
        float be = BEFF[n*BS + 16*t + lr];
        #pragma unroll
        for (int r = 0; r < 4; ++r) {
            float v = S[t][r] + be;
            float av2 = fabsf(v) - 0.01f;
            float sv = (av2 > 0.f) ? copysignf(av2, v) : 0.f;
            int pt = P0 + 16*wv + 4*lk + r;
            sout[(size_t)pt*CC + n*BS + 16*t + lr] = sv;
        }
    }
}

// ---------------------------------------------------------------------------
// P7 (v3): inverse W expansion via IN-PLACE DIF radix-2 FFT, zero-padded
// spectrum, 16 channels/block, conflict-free LDS.
//  - single buffer buf[16][257] (pad 257: lanes 0..15 span all 32 banks);
//  - l-major lane map (l = tid&15): every stage read/write conflict-free;
//  - in-place DIF: read (i, i+h) to regs -> sync -> write back -> sync;
//    output bit-reversed, epilogue reads buf[brev8(w)];
//  - 128B-aligned A reads, 64B-aligned x/out -> no line-split amplification.
// out[w] = Re(Z)+Im(Z) (verified identity with old direct form).
// LDS 33.9 KB -> 4 blocks/CU. grid (48, 256), 256 thr.
// ---------------------------------------------------------------------------
__global__ __launch_bounds__(256) void k_p7(
    const float2* __restrict__ A, const float* __restrict__ x,
    float* __restrict__ out)
{
    const int tid = threadIdx.x;
    const int row = blockIdx.y;           // 0..255 = b*HH+h
    const int c0 = blockIdx.x * 16;
    __shared__ float2 tw[128];            // e^{-2pi i t/256}, t<128
    __shared__ float2 buf[16*257];        // 32.9 KB, pad-257

    if (tid < 128) {
        float sn, cs; sincosf(TWOPI*(float)tid/256.f, &sn, &cs);
        tw[tid] = make_float2(cs, -sn);
    }
    // load kept spectrum (128B contiguous per (row,wq)), zero-pad wq >= 65
    const float2* Ar = A + (size_t)row * WKEPT * CC + c0;
    for (int idx = tid; idx < 16*256; idx += 256) {
        int l = idx & 15, w = idx >> 4;
        buf[l*257 + w] = (w < WKEPT) ? Ar[(size_t)w*CC + l]
                                     : make_float2(0.f, 0.f);
    }
    __syncthreads();

    const int l  = tid & 15;              // line (channel)
    const int tg = tid >> 4;              // 0..15
    #pragma unroll
    for (int st = 0; st < 8; ++st) {
        const int h = 128 >> st;
        float2 av[8], bv[8];
        #pragma unroll
        for (int k = 0; k < 8; ++k) {
            int t = tg + 16*k;            // 0..127
            int j = t & (h - 1);
            int i = ((t >> (7 - st)) << (8 - st)) | j;
            av[k] = buf[l*257 + i];
            bv[k] = buf[l*257 + i + h];
        }
        __syncthreads();
        #pragma unroll
        for (int k = 0; k < 8; ++k) {
            int t = tg + 16*k;
            int j = t & (h - 1);
            int i = ((t >> (7 - st)) << (8 - st)) | j;
            float2 w = tw[j << st];
            float2 a = av[k], b = bv[k];
            float dx = a.x - b.x, dy = a.y - b.y;
            buf[l*257 + i]     = make_float2(a.x + b.x, a.y + b.y);
            buf[l*257 + i + h] = make_float2(dx*w.x - dy*w.y, dx*w.y + dy*w.x);
        }
        __syncthreads();
    }
    // output is bit-reversed: Z[w] = buf[brev8(w)]
    const float scale = 1.0f / 50331648.0f;
    const size_t obase = (size_t)row * WW * CC + c0;
    for (int idx = tid; idx < 16*256; idx += 256) {
        int l2 = idx & 15, w = idx >> 4;
        int rb = (int)(__brev((unsigned)w) >> 24);
        float2 z = buf[l2*257 + rb];
        size_t g = obase + (size_t)w*CC + l2;
        out[g] = fmaf(z.x + z.y, scale, x[g]);
    }
}

// ---------------------------------------------------------------------------
// Launch. ws layout:
//   floats: Abuf (2*NPTS*CC, halves double as a_real/s_real) | BEFF
//   then ushorts: W10h,W10l,W11h,W11l,WKPh,WKPl,WKMh,WKMl (each NB*96*96)
// d_out doubles as complex buffer B.
// ---------------------------------------------------------------------------
extern "C" void kernel_launch(void* const* d_in, const int* in_sizes, int n_in,
                              void* d_out, int out_size, void* d_ws, size_t ws_size,
                              hipStream_t stream)
{
    (void)in_sizes; (void)n_in; (void)out_size; (void)ws_size;
    const float* x  = (const float*)d_in[0];
    const float* w1 = (const float*)d_in[1];
    const float* b1 = (const float*)d_in[2];
    const float* w2 = (const float*)d_in[3];
    const float* b2 = (const float*)d_in[4];

    float*  ws     = (float*)d_ws;
    float2* Abuf   = (float2*)d_ws;
    float*  a_real = ws;
    float*  s_real = ws + (size_t)NPTS*CC;
    float*  BEFF   = ws + 2*(size_t)NPTS*CC;
    unsigned short* Wq = (unsigned short*)(BEFF + NB*BS);
    const size_t WSZ = (size_t)NB*BS*BS;
    unsigned short* W10h = Wq + 0*WSZ;
    unsigned short* W10l = Wq + 1*WSZ;
    unsigned short* W11h = Wq + 2*WSZ;
    unsigned short* W11l = Wq + 3*WSZ;
    unsigned short* WKPh = Wq + 4*WSZ;
    unsigned short* WKPl = Wq + 5*WSZ;
    unsigned short* WKMh = Wq + 6*WSZ;
    unsigned short* WKMl = Wq + 7*WSZ;

    float2* Bc   = (float2*)d_out;
    float*  outf = (float*)d_out;

    k_weights<<<dim3(NB), dim3(256), 0, stream>>>(
        w1, w2, b2, W10h, W10l, W11h, W11l, WKPh, WKPl, WKMh, WKMl, BEFF);
    k_p1     <<<dim3(48, 256), dim3(256), 0, stream>>>(x, Abuf);
    k_cfft   <<<dim3(NPTS/LPB), dim3(256), 0, stream>>>(Abuf, Bc);
    k_hb_c2a <<<dim3(96, WKEPT), dim3(256), 0, stream>>>(Bc, a_real);
    k_mlp    <<<dim3(260, NB), dim3(256), 0, stream>>>(
        a_real, x, W10h, W10l, W11h, W11l, WKPh, WKPl, WKMh, WKMl,
        b1, BEFF, s_real);
    k_hb_s2c <<<dim3(48, WKEPT), dim3(256), 0, stream>>>(s_real, Bc);
    k_cfft   <<<dim3(NPTS/LPB), dim3(256), 0, stream>>>(Bc, Abuf);
    k_p7     <<<dim3(48, 256), dim3(256), 0, stream>>>(Abuf, x, outf);
}

// Round 11
// 999.321 us; speedup vs baseline: 1.1465x; 1.0236x over previous
//
#include <hip/hip_runtime.h>

#define BB 2
#define HH 128
#define WW 256
#define CC 768
#define NB 8
#define BS 96
#define WKEPT 65
#define NPTS (BB*HH*WKEPT)        // 16640 kept (b,h,w') points
#define NTOT ((size_t)BB*HH*WW*CC) // 50331648
#define TWOPI 6.283185307179586f

typedef __attribute__((ext_vector_type(8))) short bf16x8;
typedef __attribute__((ext_vector_type(4))) float f32x4;

__device__ __forceinline__ unsigned short f2bf(float f) {
    unsigned int u = __float_as_uint(f);
    u += 0x7fffu + ((u >> 16) & 1u);      // round-to-nearest-even
    return (unsigned short)(u >> 16);
}
__device__ __forceinline__ float bf2f(unsigned short s) {
    return __uint_as_float((unsigned int)s << 16);
}

// ---------------------------------------------------------------------------
// K0: precombine weights into TRANSPOSED bf16 hi/lo pairs for MFMA
// (unchanged from round 8).
// ---------------------------------------------------------------------------
__global__ __launch_bounds__(256) void k_weights(
    const float* __restrict__ w1, const float* __restrict__ w2,
    const float* __restrict__ b2,
    unsigned short* __restrict__ W10h, unsigned short* __restrict__ W10l,
    unsigned short* __restrict__ W11h, unsigned short* __restrict__ W11l,
    unsigned short* __restrict__ WKPh, unsigned short* __restrict__ WKPl,
    unsigned short* __restrict__ WKMh, unsigned short* __restrict__ WKMl,
    float* __restrict__ BEFF)
{
    const int n = blockIdx.x;
    const int tid = threadIdx.x;
    __shared__ float m_s[BS*BS];

    const float* w2a = w2 + (size_t)(0*NB + n)*BS*BS;
    const float* w2b = w2 + (size_t)(1*NB + n)*BS*BS;
    for (int idx = tid; idx < BS*BS; idx += 256)
        m_s[idx] = 0.5f*(w2a[idx] - w2b[idx]);

    const float* w1a = w1 + (size_t)(0*NB + n)*BS*BS;
    const float* w1b = w1 + (size_t)(1*NB + n)*BS*BS;
    for (int idx = tid; idx < BS*BS; idx += 256) {
        int o = idx / BS, k = idx - o*BS;          // dest [o][k]
        float v0 = w1a[k*BS + o];
        unsigned short h0 = f2bf(v0);
        unsigned short l0 = f2bf(v0 - bf2f(h0));
        W10h[n*BS*BS + idx] = h0;  W10l[n*BS*BS + idx] = l0;
        float v1 = w1b[k*BS + o];
        unsigned short h1 = f2bf(v1);
        unsigned short l1 = f2bf(v1 - bf2f(h1));
        W11h[n*BS*BS + idx] = h1;  W11l[n*BS*BS + idx] = l1;
    }
    __syncthreads();

    for (int idx = tid; idx < BS*BS; idx += 256) {
        int i = idx / BS, o = idx - i*BS;
        float p_io = 0.5f*(w2a[idx] + w2b[idx]);
        float m_io = m_s[idx];
        float accK = 0.f, accN = 0.f;
        for (int j = 0; j < BS; ++j) {
            float p_ij = 0.5f*(w2a[i*BS + j] + w2b[i*BS + j]);
            float mjo  = m_s[j*BS + o];
            accK += p_ij * mjo;
            accN += m_s[i*BS + j] * mjo;
        }
        float valK = p_io + accK;
        float valN = p_io + m_io + accN;
        float wkp = 0.5f*(valK + valN);
        float wkm = 0.5f*(valK - valN);
        int d = n*BS*BS + o*BS + i;                // transposed [o][k=i]
        unsigned short hp = f2bf(wkp);
        WKPh[d] = hp;  WKPl[d] = f2bf(wkp - bf2f(hp));
        unsigned short hm = f2bf(wkm);
        WKMh[d] = hm;  WKMl[d] = f2bf(wkm - bf2f(hm));
    }
    if (tid < BS) {
        const float* b2a = b2 + (0*NB + n)*BS;
        const float* b2b = b2 + (1*NB + n)*BS;
        float acc = b2a[tid] + b2b[tid];
        for (int j = 0; j < BS; ++j) acc += b2a[j] * m_s[j*BS + tid];
        BEFF[n*BS + tid] = acc;
    }
}

// ---------------------------------------------------------------------------
// P1: forward W-axis via 256-pt Stockham FFT, channel-pair packing
// (unchanged from round 7).
// ---------------------------------------------------------------------------
__global__ __launch_bounds__(256) void k_p1(
    const float* __restrict__ x, float2* __restrict__ out)
{
    const int tid = threadIdx.x;
    const int row = blockIdx.y;           // 0..255 = b*HH+h
    const int c0 = blockIdx.x * 16;
    __shared__ float2 tw[256];
    __shared__ float2 bufA[8*256];        // 16 KB
    __shared__ float2 bufB[8*256];        // 16 KB

    {
        float sn, cs; sincosf(TWOPI*(float)tid/256.f, &sn, &cs);
        tw[tid] = make_float2(cs, -sn);
    }
    const float* xr = x + (size_t)row * WW * CC + c0;
    for (int idx = tid; idx < 2048; idx += 256) {
        int l = idx & 7, w = idx >> 3;
        const float2 v = *(const float2*)(xr + (size_t)w*CC + 2*l);
        bufA[l*256 + w] = v;
    }
    __syncthreads();

    float2* src = bufA;
    float2* dst = bufB;
    const int t  = tid & 127;
    const int l0 = tid >> 7;
    #pragma unroll
    for (int st = 0; st < 8; ++st) {
        const int s = 1 << st;
        const int q = t & (s - 1);
        const int p = t >> st;
        const float2 w = tw[p << st];
        #pragma unroll
        for (int k = 0; k < 4; ++k) {
            int base = (l0 + 2*k) * 256;
            float2 a = src[base + q + s*p];
            float2 b = src[base + q + s*p + 128];
            float dx = a.x - b.x, dy = a.y - b.y;
            dst[base + q + 2*s*p]     = make_float2(a.x + b.x, a.y + b.y);
            dst[base + q + 2*s*p + s] = make_float2(dx*w.x - dy*w.y, dx*w.y + dy*w.x);
        }
        __syncthreads();
        float2* tmp = src; src = dst; dst = tmp;
    }
    for (int idx = tid; idx < 8*WKEPT; idx += 256) {
        int l = idx & 7, wp = idx >> 3;
        float2 Z  = src[l*256 + wp];
        float2 Zm = src[l*256 + ((256 - wp) & 255)];
        float2 U = make_float2(0.5f*(Z.x + Zm.x), 0.5f*(Z.y - Zm.y));
        float2 V = make_float2(0.5f*(Z.y + Zm.y), 0.5f*(Zm.x - Z.x));
        size_t g = (size_t)(row*WKEPT + wp)*CC + c0 + 2*l;
        out[g]     = U;
        out[g + 1] = V;
    }
}

// ---------------------------------------------------------------------------
// P2/P6: C-axis 768-pt FFT per line (unchanged).
// ---------------------------------------------------------------------------
#define LPB 4
__global__ __launch_bounds__(256) void k_cfft(
    const float2* __restrict__ in, float2* __restrict__ out)
{
    __shared__ float2 tw[CC];
    __shared__ float2 bufA[LPB*CC];
    __shared__ float2 bufB[LPB*CC];
    const int tid = threadIdx.x;
    const size_t line0 = (size_t)blockIdx.x * LPB;

    for (int t = tid; t < CC; t += 256) {
        float sn, cs; sincosf(TWOPI * (float)t / 768.0f, &sn, &cs);
        tw[t] = make_float2(cs, -sn);
    }
    for (int idx = tid; idx < LPB*CC; idx += 256) {
        int l = idx / CC, c = idx - l*CC;
        int m = c / 3, j = c - 3*m;
        bufA[l*CC + j*256 + m] = in[(line0 + l)*CC + c];
    }
    __syncthreads();

    float2* src = bufA;
    float2* dst = bufB;
    #pragma unroll
    for (int st = 0; st < 8; ++st) {
        const int s = 1 << st;
        const int h = 128 >> st;
        for (int item = tid; item < LPB*3*128; item += 256) {
            int sub = item >> 7;
            int t   = item & 127;
            int q = t & (s - 1);
            int p = t >> st;
            float2 a = src[sub*256 + q + s*p];
            float2 b = src[sub*256 + q + s*(p + h)];
            float2 w = tw[p * (3 << st)];
            float dx = a.x - b.x, dy = a.y - b.y;
            dst[sub*256 + q + s*(2*p)]     = make_float2(a.x + b.x, a.y + b.y);
            dst[sub*256 + q + s*(2*p + 1)] = make_float2(dx*w.x - dy*w.y, dx*w.y + dy*w.x);
        }
        __syncthreads();
        float2* tmp = src; src = dst; dst = tmp;
    }
    for (int idx = tid; idx < LPB*CC; idx += 256) {
        int l = idx / CC, cp = idx - l*CC;
        int r = cp & 255;
        float2 S0 = src[(l*3 + 0)*256 + r];
        float2 S1 = src[(l*3 + 1)*256 + r];
        float2 S2 = src[(l*3 + 2)*256 + r];
        float2 w1 = tw[cp];
        int i2 = 2*cp; if (i2 >= CC) i2 -= CC;
        float2 w2 = tw[i2];
        float fr = S0.x + w1.x*S1.x - w1.y*S1.y + w2.x*S2.x - w2.y*S2.y;
        float fi = S0.y + w1.x*S1.y + w1.y*S1.x + w2.x*S2.y + w2.y*S2.x;
        out[(line0 + l)*CC + cp] = make_float2(fr, fi);
    }
}

// ---------------------------------------------------------------------------
// P3: H-axis via 128-pt radix-2 Stockham FFT (unchanged).
// ---------------------------------------------------------------------------
__global__ __launch_bounds__(256) void k_hb_c2a(
    const float2* __restrict__ in, float* __restrict__ aout)
{
    const int tid = threadIdx.x;
    const int wp = blockIdx.y;
    const int c0 = blockIdx.x * 8;
    __shared__ float2 tw[128];
    __shared__ float2 bufA[16*128];
    __shared__ float2 bufB[16*128];

    if (tid < 128) {
        float sn, cs; sincosf(TWOPI*(float)tid/128.f, &sn, &cs);
        tw[tid] = make_float2(cs, -sn);
    }
    for (int idx = tid; idx < 1024; idx += 256) {
        int cl = idx & 7, h = idx >> 3;
        float2 z0 = in[(size_t)((0*HH + h)*WKEPT + wp)*CC + c0 + cl];
        float2 z1 = in[(size_t)((1*HH + h)*WKEPT + wp)*CC + c0 + cl];
        bufA[(2*cl+0)*128 + h] = make_float2(z0.x+z1.x, z0.y+z1.y);
        bufA[(2*cl+1)*128 + h] = make_float2(z0.x-z1.x, z0.y-z1.y);
    }
    __syncthreads();

    float2* src = bufA;
    float2* dst = bufB;
    const int t  = tid & 63;
    const int l0 = tid >> 6;
    #pragma unroll
    for (int st = 0; st < 7; ++st) {
        const int s = 1 << st;
        const int q = t & (s - 1);
        const int p = t >> st;
        const float2 w = tw[p << st];
        #pragma unroll
        for (int k = 0; k < 4; ++k) {
            int base = (l0 + 4*k) * 128;
            float2 a = src[base + q + s*p];
            float2 b = src[base + q + s*p + 64];
            float dx = a.x - b.x, dy = a.y - b.y;
            dst[base + q + 2*s*p]     = make_float2(a.x + b.x, a.y + b.y);
            dst[base + q + 2*s*p + s] = make_float2(dx*w.x - dy*w.y, dx*w.y + dy*w.x);
        }
        __syncthreads();
        float2* tmp = src; src = dst; dst = tmp;
    }
    for (int idx = tid; idx < 2048; idx += 256) {
        int cl = idx & 7;
        int hp = (idx >> 3) & 127;
        int uv = idx >> 10;
        float2 z = src[(2*cl + uv)*128 + hp];
        aout[(size_t)((uv*HH + hp)*WKEPT + wp)*CC + c0 + cl] = z.x + z.y;
    }
}

// ---------------------------------------------------------------------------
// P5: H-axis FFT on REAL s via complex packing (unchanged).
// ---------------------------------------------------------------------------
__global__ __launch_bounds__(256) void k_hb_s2c(
    const float* __restrict__ sreal, float2* __restrict__ out)
{
    const int tid = threadIdx.x;
    const int wp = blockIdx.y;
    const int c0 = blockIdx.x * 16;
    __shared__ float2 tw[128];
    __shared__ float2 bufA[16*128];
    __shared__ float2 bufB[16*128];

    if (tid < 128) {
        float sn, cs; sincosf(TWOPI*(float)tid/128.f, &sn, &cs);
        tw[tid] = make_float2(cs, -sn);
    }
    for (int idx = tid; idx < 2048; idx += 256) {
        int cl = idx & 15, h = idx >> 4;
        float s0 = sreal[(size_t)((0*HH + h)*WKEPT + wp)*CC + c0 + cl];
        float s1 = sreal[(size_t)((1*HH + h)*WKEPT + wp)*CC + c0 + cl];
        bufA[cl*128 + h] = make_float2(s0 + s1, s0 - s1);   // z = u + i v
    }
    __syncthreads();

    float2* src = bufA;
    float2* dst = bufB;
    const int t  = tid & 63;
    const int l0 = tid >> 6;
    #pragma unroll
    for (int st = 0; st < 7; ++st) {
        const int s = 1 << st;
        const int q = t & (s - 1);
        const int p = t >> st;
        const float2 w = tw[p << st];
        #pragma unroll
        for (int k = 0; k < 4; ++k) {
            int base = (l0 + 4*k) * 128;
            float2 a = src[base + q + s*p];
            float2 b = src[base + q + s*p + 64];
            float dx = a.x - b.x, dy = a.y - b.y;
            dst[base + q + 2*s*p]     = make_float2(a.x + b.x, a.y + b.y);
            dst[base + q + 2*s*p + s] = make_float2(dx*w.x - dy*w.y, dx*w.y + dy*w.x);
        }
        __syncthreads();
        float2* tmp = src; src = dst; dst = tmp;
    }
    for (int idx = tid; idx < 2048; idx += 256) {
        int cl = idx & 15;
        int hp = idx >> 4;
        float2 A  = src[cl*128 + hp];
        float2 Zm = src[cl*128 + ((128 - hp) & 127)];
        float2 U = make_float2(0.5f*(A.x + Zm.x), 0.5f*(A.y - Zm.y));
        float2 V = make_float2(0.5f*(A.y + Zm.y), 0.5f*(Zm.x - A.x));
        out[(size_t)((0*HH + hp)*WKEPT + wp)*CC + c0 + cl] = U;
        out[(size_t)((1*HH + hp)*WKEPT + wp)*CC + c0 + cl] = V;
    }
}

// ---------------------------------------------------------------------------
// P4 (MFMA): fused MLP on matrix cores (unchanged from round 8).
// ---------------------------------------------------------------------------
__global__ __launch_bounds__(256, 2) void k_mlp(
    const float* __restrict__ a, const float* __restrict__ x,
    const unsigned short* __restrict__ W10h, const unsigned short* __restrict__ W10l,
    const unsigned short* __restrict__ W11h, const unsigned short* __restrict__ W11l,
    const unsigned short* __restrict__ WKPh, const unsigned short* __restrict__ WKPl,
    const unsigned short* __restrict__ WKMh, const unsigned short* __restrict__ WKMl,
    const float* __restrict__ b1, const float* __restrict__ BEFF,
    float* __restrict__ sout)
{
    const int tid = threadIdx.x;
    const int n = blockIdx.y;
    const int P0 = blockIdx.x * 64;
    __shared__ unsigned short Wh_A[96*48], Wl_A[96*48];
    __shared__ unsigned short Wh_B[96*48], Wl_B[96*48];
    __shared__ unsigned short PMp[64*104], PMm[64*104];

    const int lane = tid & 63;
    const int wv = tid >> 6;
    const int lr = lane & 15;
    const int lk = lane >> 4;

    const int Pld = P0 + 16*wv + lr;
    int bb = Pld / (HH*WKEPT);
    int rem = Pld - bb*(HH*WKEPT);
    int h = rem / WKEPT;
    int wq = rem - h*WKEPT;
    int hh2 = (HH - h) & (HH-1);
    int ww2 = (WW - wq) & (WW-1);
    const float* aRow  = a + (size_t)Pld*CC + n*BS;
    const float* anRow = x + (size_t)((bb*HH + hh2)*WW + ww2)*CC + n*BS;

    f32x4 T1[6], T2[6];
    #pragma unroll
    for (int t = 0; t < 6; ++t) {
        T1[t] = (f32x4){0.f,0.f,0.f,0.f};
        T2[t] = (f32x4){0.f,0.f,0.f,0.f};
    }

    for (int ks = 0; ks < 3; ++ks) {
        __syncthreads();
        for (int idx = tid; idx < 96*16; idx += 256) {
            int o = idx >> 4, kp = (idx & 15) << 1;
            int g = n*BS*BS + o*BS + ks*32 + kp;
            *(ushort2*)&Wh_A[o*48 + kp] = *(const ushort2*)&W10h[g];
            *(ushort2*)&Wl_A[o*48 + kp] = *(const ushort2*)&W10l[g];
            *(ushort2*)&Wh_B[o*48 + kp] = *(const ushort2*)&W11h[g];
            *(ushort2*)&Wl_B[o*48 + kp] = *(const ushort2*)&W11l[g];
        }
        __syncthreads();

        const int kseg = ks*32 + 8*lk;
        float4 a0 = *(const float4*)(aRow + kseg);
        float4 a1 = *(const float4*)(aRow + kseg + 4);
        float4 n0 = *(const float4*)(anRow + kseg);
        float4 n1 = *(const float4*)(anRow + kseg + 4);
        bf16x8 uF, vF;
        uF[0] = (short)f2bf(0.5f*(a0.x + n0.x));  vF[0] = (short)f2bf(0.5f*(a0.x - n0.x));
        uF[1] = (short)f2bf(0.5f*(a0.y + n0.y));  vF[1] = (short)f2bf(0.5f*(a0.y - n0.y));
        uF[2] = (short)f2bf(0.5f*(a0.z + n0.z));  vF[2] = (short)f2bf(0.5f*(a0.z - n0.z));
        uF[3] = (short)f2bf(0.5f*(a0.w + n0.w));  vF[3] = (short)f2bf(0.5f*(a0.w - n0.w));
        uF[4] = (short)f2bf(0.5f*(a1.x + n1.x));  vF[4] = (short)f2bf(0.5f*(a1.x - n1.x));
        uF[5] = (short)f2bf(0.5f*(a1.y + n1.y));  vF[5] = (short)f2bf(0.5f*(a1.y - n1.y));
        uF[6] = (short)f2bf(0.5f*(a1.z + n1.z));  vF[6] = (short)f2bf(0.5f*(a1.z - n1.z));
        uF[7] = (short)f2bf(0.5f*(a1.w + n1.w));  vF[7] = (short)f2bf(0.5f*(a1.w - n1.w));

        #pragma unroll
        for (int t = 0; t < 6; ++t) {
            int wb = (16*t + lr)*48 + 8*lk;
            bf16x8 bh = *(const bf16x8*)&Wh_A[wb];
            T1[t] = __builtin_amdgcn_mfma_f32_16x16x32_bf16(uF, bh, T1[t], 0, 0, 0);
            bf16x8 bl = *(const bf16x8*)&Wl_A[wb];
            T1[t] = __builtin_amdgcn_mfma_f32_16x16x32_bf16(uF, bl, T1[t], 0, 0, 0);
            bf16x8 ch = *(const bf16x8*)&Wh_B[wb];
            T2[t] = __builtin_amdgcn_mfma_f32_16x16x32_bf16(vF, ch, T2[t], 0, 0, 0);
            bf16x8 cl = *(const bf16x8*)&Wl_B[wb];
            T2[t] = __builtin_amdgcn_mfma_f32_16x16x32_bf16(vF, cl, T2[t], 0, 0, 0);
        }
    }

    #pragma unroll
    for (int t = 0; t < 6; ++t) {
        float bk = b1[(0*NB + n)*BS + 16*t + lr];
        float bn = b1[(1*NB + n)*BS + 16*t + lr];
        #pragma unroll
        for (int r = 0; r < 4; ++r) {
            float ok = fmaxf(T1[t][r] + T2[t][r] + bk, 0.f);
            float on = fmaxf(T1[t][r] - T2[t][r] + bn, 0.f);
            int pl = 16*wv + 4*lk + r;
            PMp[pl*104 + 16*t + lr] = f2bf(ok + on);
            PMm[pl*104 + 16*t + lr] = f2bf(ok - on);
        }
    }

    f32x4 S[6];
    #pragma unroll
    for (int t = 0; t < 6; ++t) S[t] = (f32x4){0.f,0.f,0.f,0.f};
    for (int ks = 0; ks < 3; ++ks) {
        __syncthreads();
        for (int idx = tid; idx < 96*16; idx += 256) {
            int o = idx >> 4, kp = (idx & 15) << 1;
            int g = n*BS*BS + o*BS + ks*32 + kp;
            *(ushort2*)&Wh_A[o*48 + kp] = *(const ushort2*)&WKPh[g];
            *(ushort2*)&Wl_A[o*48 + kp] = *(const ushort2*)&WKPl[g];
            *(ushort2*)&Wh_B[o*48 + kp] = *(const ushort2*)&WKMh[g];
            *(ushort2*)&Wl_B[o*48 + kp] = *(const ushort2*)&WKMl[g];
        }
        __syncthreads();

        const int kseg = ks*32 + 8*lk;
        bf16x8 pF = *(const bf16x8*)&PMp[(16*wv + lr)*104 + kseg];
        bf16x8 mF = *(const bf16x8*)&PMm[(16*wv + lr)*104 + kseg];
        #pragma unroll
        for (int t = 0; t < 6; ++t) {
            int wb = (16*t + lr)*48 + 8*lk;
            bf16x8 bh = *(const bf16x8*)&Wh_A[wb];
            S[t] = __builtin_amdgcn_mfma_f32_16x16x32_bf16(pF, bh, S[t], 0, 0, 0);
            bf16x8 bl = *(const bf16x8*)&Wl_A[wb];
            S[t] = __builtin_amdgcn_mfma_f32_16x16x32_bf16(pF, bl, S[t], 0, 0, 0);
            bf16x8 ch = *(const bf16x8*)&Wh_B[wb];
            S[t] = __builtin_amdgcn_mfma_f32_16x16x32_bf16(mF, ch, S[t], 0, 0, 0);
            bf16x8 cl = *(const bf16x8*)&Wl_B[wb];
            S[t] = __builtin_amdgcn_mfma_f32_16x16x32_bf16(mF, cl, S[t], 0, 0, 0);
        }
    }

    #pragma unroll
    for (int t = 0; t < 6; ++t) {
        float be = BEFF[n*BS + 16*t + lr];
        #pragma unroll
        for (int r = 0; r < 4; ++r) {
            float v = S[t][r] + be;
            float av2 = fabsf(v) - 0.01f;
            float sv = (av2 > 0.f) ? copysignf(av2, v) : 0.f;
            int pt = P0 + 16*wv + 4*lk + r;
            sout[(size_t)pt*CC + n*BS + 16*t + lr] = sv;
        }
    }
}

// ---------------------------------------------------------------------------
// P7 (v4): register-resident DIF FFT, one LDS transpose, 2 barriers.
// Thread (l=tid&15, tg=tid>>4) first owns the 16 points i = tg + 16m of its
// line (m=0..15): stages h=128,64,32,16 are THREAD-LOCAL (i mod 16 fixed).
// One transpose via buf[16][257], then thread owns i = 16*tg + m: stages
// h=8,4,2,1 thread-local too. Same verified DIF math/twiddles as round 10
// (j = i&(h-1), tw[j<<st], bit-reversed output, w = brev8(i) epilogue).
// DS ops/thread: 256 -> 96; barriers: 16 -> 2.
// LDS 33.9 KB -> 4 blocks/CU. grid (48, 256), 256 thr.
// ---------------------------------------------------------------------------
__global__ __launch_bounds__(256) void k_p7(
    const float2* __restrict__ A, const float* __restrict__ x,
    float* __restrict__ out)
{
    const int tid = threadIdx.x;
    const int row = blockIdx.y;           // 0..255 = b*HH+h
    const int c0 = blockIdx.x * 16;
    __shared__ float2 tw[128];            // e^{-2pi i t/256}, t<128
    __shared__ float2 buf[16*257];        // 32.9 KB transpose buffer

    if (tid < 128) {
        float sn, cs; sincosf(TWOPI*(float)tid/256.f, &sn, &cs);
        tw[tid] = make_float2(cs, -sn);
    }
    const int l  = tid & 15;              // line (channel)
    const int tg = tid >> 4;              // 0..15

    // load: p[m] = spectrum at index i = tg + 16m (zero-pad w >= 65)
    float2 p[16];
    const float2* Ar = A + (size_t)row * WKEPT * CC + c0;
    #pragma unroll
    for (int m = 0; m < 16; ++m) {
        int w = tg + 16*m;
        p[m] = (w < WKEPT) ? Ar[(size_t)w*CC + l] : make_float2(0.f, 0.f);
    }
    __syncthreads();   // tw ready

    // ---- stages st=0..3 (h = 128,64,32,16): thread-local on i = tg+16m ----
    #pragma unroll
    for (int st = 0; st < 4; ++st) {
        const int h16 = 8 >> st;          // pair distance in m
        #pragma unroll
        for (int g = 0; g < (1 << st); ++g) {
            #pragma unroll
            for (int ml = 0; ml < (8 >> st); ++ml) {
                int m = g*2*h16 + ml;
                int mp = m + h16;
                float2 a = p[m], b = p[mp];
                float2 w = tw[(tg + 16*ml) << st];   // j = i&(h-1) = tg+16*ml
                float dx = a.x - b.x, dy = a.y - b.y;
                p[m]  = make_float2(a.x + b.x, a.y + b.y);
                p[mp] = make_float2(dx*w.x - dy*w.y, dx*w.y + dy*w.x);
            }
        }
    }

    // ---- transpose: i = tg+16m  ->  i = 16*tg + m ----
    #pragma unroll
    for (int m = 0; m < 16; ++m)
        buf[l*257 + tg + 16*m] = p[m];
    __syncthreads();
    #pragma unroll
    for (int m = 0; m < 16; ++m)
        p[m] = buf[l*257 + 16*tg + m];

    // ---- stages st=4..7 (h = 8,4,2,1): thread-local on i = 16*tg + m ----
    #pragma unroll
    for (int st = 4; st < 8; ++st) {
        const int h = 128 >> st;          // 8,4,2,1
        #pragma unroll
        for (int g = 0; g < (1 << (st-4)); ++g) {
            #pragma unroll
            for (int ml = 0; ml < (128 >> st); ++ml) {
                int m = g*2*h + ml;
                int mp = m + h;
                float2 a = p[m], b = p[mp];
                float2 w = tw[ml << st];             // j = i&(h-1) = ml
                float dx = a.x - b.x, dy = a.y - b.y;
                p[m]  = make_float2(a.x + b.x, a.y + b.y);
                p[mp] = make_float2(dx*w.x - dy*w.y, dx*w.y + dy*w.x);
            }
        }
    }

    // ---- epilogue: Z[w] = value at i = brev8(w)  ->  w = brev8(i) ----
    const float scale = 1.0f / 50331648.0f;
    const size_t obase = (size_t)row * WW * CC + c0;
    #pragma unroll
    for (int m = 0; m < 16; ++m) {
        int i = 16*tg + m;
        int w = (int)(__brev((unsigned)i) >> 24);
        size_t g = obase + (size_t)w*CC + l;
        out[g] = fmaf(p[m].x + p[m].y, scale, x[g]);
    }
}

// ---------------------------------------------------------------------------
// Launch. ws layout:
//   floats: Abuf (2*NPTS*CC, halves double as a_real/s_real) | BEFF
//   then ushorts: W10h,W10l,W11h,W11l,WKPh,WKPl,WKMh,WKMl (each NB*96*96)
// d_out doubles as complex buffer B.
// ---------------------------------------------------------------------------
extern "C" void kernel_launch(void* const* d_in, const int* in_sizes, int n_in,
                              void* d_out, int out_size, void* d_ws, size_t ws_size,
                              hipStream_t stream)
{
    (void)in_sizes; (void)n_in; (void)out_size; (void)ws_size;
    const float* x  = (const float*)d_in[0];
    const float* w1 = (const float*)d_in[1];
    const float* b1 = (const float*)d_in[2];
    const float* w2 = (const float*)d_in[3];
    const float* b2 = (const float*)d_in[4];

    float*  ws     = (float*)d_ws;
    float2* Abuf   = (float2*)d_ws;
    float*  a_real = ws;
    float*  s_real = ws + (size_t)NPTS*CC;
    float*  BEFF   = ws + 2*(size_t)NPTS*CC;
    unsigned short* Wq = (unsigned short*)(BEFF + NB*BS);
    const size_t WSZ = (size_t)NB*BS*BS;
    unsigned short* W10h = Wq + 0*WSZ;
    unsigned short* W10l = Wq + 1*WSZ;
    unsigned short* W11h = Wq + 2*WSZ;
    unsigned short* W11l = Wq + 3*WSZ;
    unsigned short* WKPh = Wq + 4*WSZ;
    unsigned short* WKPl = Wq + 5*WSZ;
    unsigned short* WKMh = Wq + 6*WSZ;
    unsigned short* WKMl = Wq + 7*WSZ;

    float2* Bc   = (float2*)d_out;
    float*  outf = (float*)d_out;

    k_weights<<<dim3(NB), dim3(256), 0, stream>>>(
        w1, w2, b2, W10h, W10l, W11h, W11l, WKPh, WKPl, WKMh, WKMl, BEFF);
    k_p1     <<<dim3(48, 256), dim3(256), 0, stream>>>(x, Abuf);
    k_cfft   <<<dim3(NPTS/LPB), dim3(256), 0, stream>>>(Abuf, Bc);
    k_hb_c2a <<<dim3(96, WKEPT), dim3(256), 0, stream>>>(Bc, a_real);
    k_mlp    <<<dim3(260, NB), dim3(256), 0, stream>>>(
        a_real, x, W10h, W10l, W11h, W11l, WKPh, WKPl, WKMh, WKMl,
        b1, BEFF, s_real);
    k_hb_s2c <<<dim3(48, WKEPT), dim3(256), 0, stream>>>(s_real, Bc);
    k_cfft   <<<dim3(NPTS/LPB), dim3(256), 0, stream>>>(Bc, Abuf);
    k_p7     <<<dim3(48, 256), dim3(256), 0, stream>>>(Abuf, x, outf);
}

// Round 12
// 967.175 us; speedup vs baseline: 1.1846x; 1.0332x over previous
//
#include <hip/hip_runtime.h>

#define BB 2
#define HH 128
#define WW 256
#define CC 768
#define NB 8
#define BS 96
#define WKEPT 65
#define NPTS (BB*HH*WKEPT)        // 16640 kept (b,h,w') points
#define NTOT ((size_t)BB*HH*WW*CC) // 50331648
#define TWOPI 6.283185307179586f

typedef __attribute__((ext_vector_type(8))) short bf16x8;
typedef __attribute__((ext_vector_type(4))) float f32x4;

__device__ __forceinline__ unsigned short f2bf(float f) {
    unsigned int u = __float_as_uint(f);
    u += 0x7fffu + ((u >> 16) & 1u);      // round-to-nearest-even
    return (unsigned short)(u >> 16);
}
__device__ __forceinline__ float bf2f(unsigned short s) {
    return __uint_as_float((unsigned int)s << 16);
}
// packed complex <-> bf16x2 in one uint (global spectra storage only;
// all LDS compute stays fp32)
__device__ __forceinline__ unsigned c2bf(float2 v) {
    return (unsigned)f2bf(v.x) | ((unsigned)f2bf(v.y) << 16);
}
__device__ __forceinline__ float2 bf2c(unsigned u) {
    return make_float2(bf2f((unsigned short)(u & 0xffffu)),
                       bf2f((unsigned short)(u >> 16)));
}

// ---------------------------------------------------------------------------
// K0: precombine weights into TRANSPOSED bf16 hi/lo pairs for MFMA
// (unchanged from round 8).
// ---------------------------------------------------------------------------
__global__ __launch_bounds__(256) void k_weights(
    const float* __restrict__ w1, const float* __restrict__ w2,
    const float* __restrict__ b2,
    unsigned short* __restrict__ W10h, unsigned short* __restrict__ W10l,
    unsigned short* __restrict__ W11h, unsigned short* __restrict__ W11l,
    unsigned short* __restrict__ WKPh, unsigned short* __restrict__ WKPl,
    unsigned short* __restrict__ WKMh, unsigned short* __restrict__ WKMl,
    float* __restrict__ BEFF)
{
    const int n = blockIdx.x;
    const int tid = threadIdx.x;
    __shared__ float m_s[BS*BS];

    const float* w2a = w2 + (size_t)(0*NB + n)*BS*BS;
    const float* w2b = w2 + (size_t)(1*NB + n)*BS*BS;
    for (int idx = tid; idx < BS*BS; idx += 256)
        m_s[idx] = 0.5f*(w2a[idx] - w2b[idx]);

    const float* w1a = w1 + (size_t)(0*NB + n)*BS*BS;
    const float* w1b = w1 + (size_t)(1*NB + n)*BS*BS;
    for (int idx = tid; idx < BS*BS; idx += 256) {
        int o = idx / BS, k = idx - o*BS;          // dest [o][k]
        float v0 = w1a[k*BS + o];
        unsigned short h0 = f2bf(v0);
        unsigned short l0 = f2bf(v0 - bf2f(h0));
        W10h[n*BS*BS + idx] = h0;  W10l[n*BS*BS + idx] = l0;
        float v1 = w1b[k*BS + o];
        unsigned short h1 = f2bf(v1);
        unsigned short l1 = f2bf(v1 - bf2f(h1));
        W11h[n*BS*BS + idx] = h1;  W11l[n*BS*BS + idx] = l1;
    }
    __syncthreads();

    for (int idx = tid; idx < BS*BS; idx += 256) {
        int i = idx / BS, o = idx - i*BS;
        float p_io = 0.5f*(w2a[idx] + w2b[idx]);
        float m_io = m_s[idx];
        float accK = 0.f, accN = 0.f;
        for (int j = 0; j < BS; ++j) {
            float p_ij = 0.5f*(w2a[i*BS + j] + w2b[i*BS + j]);
            float mjo  = m_s[j*BS + o];
            accK += p_ij * mjo;
            accN += m_s[i*BS + j] * mjo;
        }
        float valK = p_io + accK;
        float valN = p_io + m_io + accN;
        float wkp = 0.5f*(valK + valN);
        float wkm = 0.5f*(valK - valN);
        int d = n*BS*BS + o*BS + i;                // transposed [o][k=i]
        unsigned short hp = f2bf(wkp);
        WKPh[d] = hp;  WKPl[d] = f2bf(wkp - bf2f(hp));
        unsigned short hm = f2bf(wkm);
        WKMh[d] = hm;  WKMl[d] = f2bf(wkm - bf2f(hm));
    }
    if (tid < BS) {
        const float* b2a = b2 + (0*NB + n)*BS;
        const float* b2b = b2 + (1*NB + n)*BS;
        float acc = b2a[tid] + b2b[tid];
        for (int j = 0; j < BS; ++j) acc += b2a[j] * m_s[j*BS + tid];
        BEFF[n*BS + tid] = acc;
    }
}

// ---------------------------------------------------------------------------
// P1: forward W-axis via 256-pt Stockham FFT, channel-pair packing.
// Output spectra now packed bf16x2 (uint). Compute unchanged (fp32 LDS).
// ---------------------------------------------------------------------------
__global__ __launch_bounds__(256) void k_p1(
    const float* __restrict__ x, unsigned* __restrict__ out)
{
    const int tid = threadIdx.x;
    const int row = blockIdx.y;           // 0..255 = b*HH+h
    const int c0 = blockIdx.x * 16;
    __shared__ float2 tw[256];
    __shared__ float2 bufA[8*256];        // 16 KB
    __shared__ float2 bufB[8*256];        // 16 KB

    {
        float sn, cs; sincosf(TWOPI*(float)tid/256.f, &sn, &cs);
        tw[tid] = make_float2(cs, -sn);
    }
    const float* xr = x + (size_t)row * WW * CC + c0;
    for (int idx = tid; idx < 2048; idx += 256) {
        int l = idx & 7, w = idx >> 3;
        const float2 v = *(const float2*)(xr + (size_t)w*CC + 2*l);
        bufA[l*256 + w] = v;
    }
    __syncthreads();

    float2* src = bufA;
    float2* dst = bufB;
    const int t  = tid & 127;
    const int l0 = tid >> 7;
    #pragma unroll
    for (int st = 0; st < 8; ++st) {
        const int s = 1 << st;
        const int q = t & (s - 1);
        const int p = t >> st;
        const float2 w = tw[p << st];
        #pragma unroll
        for (int k = 0; k < 4; ++k) {
            int base = (l0 + 2*k) * 256;
            float2 a = src[base + q + s*p];
            float2 b = src[base + q + s*p + 128];
            float dx = a.x - b.x, dy = a.y - b.y;
            dst[base + q + 2*s*p]     = make_float2(a.x + b.x, a.y + b.y);
            dst[base + q + 2*s*p + s] = make_float2(dx*w.x - dy*w.y, dx*w.y + dy*w.x);
        }
        __syncthreads();
        float2* tmp = src; src = dst; dst = tmp;
    }
    for (int idx = tid; idx < 8*WKEPT; idx += 256) {
        int l = idx & 7, wp = idx >> 3;
        float2 Z  = src[l*256 + wp];
        float2 Zm = src[l*256 + ((256 - wp) & 255)];
        float2 U = make_float2(0.5f*(Z.x + Zm.x), 0.5f*(Z.y - Zm.y));
        float2 V = make_float2(0.5f*(Z.y + Zm.y), 0.5f*(Zm.x - Z.x));
        size_t g = (size_t)(row*WKEPT + wp)*CC + c0 + 2*l;
        *(uint2*)&out[g] = make_uint2(c2bf(U), c2bf(V));
    }
}

// ---------------------------------------------------------------------------
// P2/P6: C-axis 768-pt FFT per line. IO now packed bf16x2 (uint);
// FFT compute unchanged (fp32 LDS).
// ---------------------------------------------------------------------------
#define LPB 4
__global__ __launch_bounds__(256) void k_cfft(
    const unsigned* __restrict__ in, unsigned* __restrict__ out)
{
    __shared__ float2 tw[CC];
    __shared__ float2 bufA[LPB*CC];
    __shared__ float2 bufB[LPB*CC];
    const int tid = threadIdx.x;
    const size_t line0 = (size_t)blockIdx.x * LPB;

    for (int t = tid; t < CC; t += 256) {
        float sn, cs; sincosf(TWOPI * (float)t / 768.0f, &sn, &cs);
        tw[t] = make_float2(cs, -sn);
    }
    for (int idx = tid; idx < LPB*CC; idx += 256) {
        int l = idx / CC, c = idx - l*CC;
        int m = c / 3, j = c - 3*m;
        bufA[l*CC + j*256 + m] = bf2c(in[(line0 + l)*CC + c]);
    }
    __syncthreads();

    float2* src = bufA;
    float2* dst = bufB;
    #pragma unroll
    for (int st = 0; st < 8; ++st) {
        const int s = 1 << st;
        const int h = 128 >> st;
        for (int item = tid; item < LPB*3*128; item += 256) {
            int sub = item >> 7;
            int t   = item & 127;
            int q = t & (s - 1);
            int p = t >> st;
            float2 a = src[sub*256 + q + s*p];
            float2 b = src[sub*256 + q + s*(p + h)];
            float2 w = tw[p * (3 << st)];
            float dx = a.x - b.x, dy = a.y - b.y;
            dst[sub*256 + q + s*(2*p)]     = make_float2(a.x + b.x, a.y + b.y);
            dst[sub*256 + q + s*(2*p + 1)] = make_float2(dx*w.x - dy*w.y, dx*w.y + dy*w.x);
        }
        __syncthreads();
        float2* tmp = src; src = dst; dst = tmp;
    }
    for (int idx = tid; idx < LPB*CC; idx += 256) {
        int l = idx / CC, cp = idx - l*CC;
        int r = cp & 255;
        float2 S0 = src[(l*3 + 0)*256 + r];
        float2 S1 = src[(l*3 + 1)*256 + r];
        float2 S2 = src[(l*3 + 2)*256 + r];
        float2 w1 = tw[cp];
        int i2 = 2*cp; if (i2 >= CC) i2 -= CC;
        float2 w2 = tw[i2];
        float fr = S0.x + w1.x*S1.x - w1.y*S1.y + w2.x*S2.x - w2.y*S2.y;
        float fi = S0.y + w1.x*S1.y + w1.y*S1.x + w2.x*S2.y + w2.y*S2.x;
        out[(line0 + l)*CC + cp] = c2bf(make_float2(fr, fi));
    }
}

// ---------------------------------------------------------------------------
// P3: H-axis via 128-pt radix-2 Stockham FFT. Input now bf16x2; output
// a_real stays fp32 (mlp path unchanged).
// ---------------------------------------------------------------------------
__global__ __launch_bounds__(256) void k_hb_c2a(
    const unsigned* __restrict__ in, float* __restrict__ aout)
{
    const int tid = threadIdx.x;
    const int wp = blockIdx.y;
    const int c0 = blockIdx.x * 8;
    __shared__ float2 tw[128];
    __shared__ float2 bufA[16*128];
    __shared__ float2 bufB[16*128];

    if (tid < 128) {
        float sn, cs; sincosf(TWOPI*(float)tid/128.f, &sn, &cs);
        tw[tid] = make_float2(cs, -sn);
    }
    for (int idx = tid; idx < 1024; idx += 256) {
        int cl = idx & 7, h = idx >> 3;
        float2 z0 = bf2c(in[(size_t)((0*HH + h)*WKEPT + wp)*CC + c0 + cl]);
        float2 z1 = bf2c(in[(size_t)((1*HH + h)*WKEPT + wp)*CC + c0 + cl]);
        bufA[(2*cl+0)*128 + h] = make_float2(z0.x+z1.x, z0.y+z1.y);
        bufA[(2*cl+1)*128 + h] = make_float2(z0.x-z1.x, z0.y-z1.y);
    }
    __syncthreads();

    float2* src = bufA;
    float2* dst = bufB;
    const int t  = tid & 63;
    const int l0 = tid >> 6;
    #pragma unroll
    for (int st = 0; st < 7; ++st) {
        const int s = 1 << st;
        const int q = t & (s - 1);
        const int p = t >> st;
        const float2 w = tw[p << st];
        #pragma unroll
        for (int k = 0; k < 4; ++k) {
            int base = (l0 + 4*k) * 128;
            float2 a = src[base + q + s*p];
            float2 b = src[base + q + s*p + 64];
            float dx = a.x - b.x, dy = a.y - b.y;
            dst[base + q + 2*s*p]     = make_float2(a.x + b.x, a.y + b.y);
            dst[base + q + 2*s*p + s] = make_float2(dx*w.x - dy*w.y, dx*w.y + dy*w.x);
        }
        __syncthreads();
        float2* tmp = src; src = dst; dst = tmp;
    }
    for (int idx = tid; idx < 2048; idx += 256) {
        int cl = idx & 7;
        int hp = (idx >> 3) & 127;
        int uv = idx >> 10;
        float2 z = src[(2*cl + uv)*128 + hp];
        aout[(size_t)((uv*HH + hp)*WKEPT + wp)*CC + c0 + cl] = z.x + z.y;
    }
}

// ---------------------------------------------------------------------------
// P5: H-axis FFT on REAL s via complex packing. Input s_real stays fp32;
// output spectra now bf16x2.
// ---------------------------------------------------------------------------
__global__ __launch_bounds__(256) void k_hb_s2c(
    const float* __restrict__ sreal, unsigned* __restrict__ out)
{
    const int tid = threadIdx.x;
    const int wp = blockIdx.y;
    const int c0 = blockIdx.x * 16;
    __shared__ float2 tw[128];
    __shared__ float2 bufA[16*128];
    __shared__ float2 bufB[16*128];

    if (tid < 128) {
        float sn, cs; sincosf(TWOPI*(float)tid/128.f, &sn, &cs);
        tw[tid] = make_float2(cs, -sn);
    }
    for (int idx = tid; idx < 2048; idx += 256) {
        int cl = idx & 15, h = idx >> 4;
        float s0 = sreal[(size_t)((0*HH + h)*WKEPT + wp)*CC + c0 + cl];
        float s1 = sreal[(size_t)((1*HH + h)*WKEPT + wp)*CC + c0 + cl];
        bufA[cl*128 + h] = make_float2(s0 + s1, s0 - s1);   // z = u + i v
    }
    __syncthreads();

    float2* src = bufA;
    float2* dst = bufB;
    const int t  = tid & 63;
    const int l0 = tid >> 6;
    #pragma unroll
    for (int st = 0; st < 7; ++st) {
        const int s = 1 << st;
        const int q = t & (s - 1);
        const int p = t >> st;
        const float2 w = tw[p << st];
        #pragma unroll
        for (int k = 0; k < 4; ++k) {
            int base = (l0 + 4*k) * 128;
            float2 a = src[base + q + s*p];
            float2 b = src[base + q + s*p + 64];
            float dx = a.x - b.x, dy = a.y - b.y;
            dst[base + q + 2*s*p]     = make_float2(a.x + b.x, a.y + b.y);
            dst[base + q + 2*s*p + s] = make_float2(dx*w.x - dy*w.y, dx*w.y + dy*w.x);
        }
        __syncthreads();
        float2* tmp = src; src = dst; dst = tmp;
    }
    for (int idx = tid; idx < 2048; idx += 256) {
        int cl = idx & 15;
        int hp = idx >> 4;
        float2 A  = src[cl*128 + hp];
        float2 Zm = src[cl*128 + ((128 - hp) & 127)];
        float2 U = make_float2(0.5f*(A.x + Zm.x), 0.5f*(A.y - Zm.y));
        float2 V = make_float2(0.5f*(A.y + Zm.y), 0.5f*(Zm.x - A.x));
        out[(size_t)((0*HH + hp)*WKEPT + wp)*CC + c0 + cl] = c2bf(U);
        out[(size_t)((1*HH + hp)*WKEPT + wp)*CC + c0 + cl] = c2bf(V);
    }
}

// ---------------------------------------------------------------------------
// P4 (MFMA): fused MLP on matrix cores (unchanged from round 8).
// ---------------------------------------------------------------------------
__global__ __launch_bounds__(256, 2) void k_mlp(
    const float* __restrict__ a, const float* __restrict__ x,
    const unsigned short* __restrict__ W10h, const unsigned short* __restrict__ W10l,
    const unsigned short* __restrict__ W11h, const unsigned short* __restrict__ W11l,
    const unsigned short* __restrict__ WKPh, const unsigned short* __restrict__ WKPl,
    const unsigned short* __restrict__ WKMh, const unsigned short* __restrict__ WKMl,
    const float* __restrict__ b1, const float* __restrict__ BEFF,
    float* __restrict__ sout)
{
    const int tid = threadIdx.x;
    const int n = blockIdx.y;
    const int P0 = blockIdx.x * 64;
    __shared__ unsigned short Wh_A[96*48], Wl_A[96*48];
    __shared__ unsigned short Wh_B[96*48], Wl_B[96*48];
    __shared__ unsigned short PMp[64*104], PMm[64*104];

    const int lane = tid & 63;
    const int wv = tid >> 6;
    const int lr = lane & 15;
    const int lk = lane >> 4;

    const int Pld = P0 + 16*wv + lr;
    int bb = Pld / (HH*WKEPT);
    int rem = Pld - bb*(HH*WKEPT);
    int h = rem / WKEPT;
    int wq = rem - h*WKEPT;
    int hh2 = (HH - h) & (HH-1);
    int ww2 = (WW - wq) & (WW-1);
    const float* aRow  = a + (size_t)Pld*CC + n*BS;
    const float* anRow = x + (size_t)((bb*HH + hh2)*WW + ww2)*CC + n*BS;

    f32x4 T1[6], T2[6];
    #pragma unroll
    for (int t = 0; t < 6; ++t) {
        T1[t] = (f32x4){0.f,0.f,0.f,0.f};
        T2[t] = (f32x4){0.f,0.f,0.f,0.f};
    }

    for (int ks = 0; ks < 3; ++ks) {
        __syncthreads();
        for (int idx = tid; idx < 96*16; idx += 256) {
            int o = idx >> 4, kp = (idx & 15) << 1;
            int g = n*BS*BS + o*BS + ks*32 + kp;
            *(ushort2*)&Wh_A[o*48 + kp] = *(const ushort2*)&W10h[g];
            *(ushort2*)&Wl_A[o*48 + kp] = *(const ushort2*)&W10l[g];
            *(ushort2*)&Wh_B[o*48 + kp] = *(const ushort2*)&W11h[g];
            *(ushort2*)&Wl_B[o*48 + kp] = *(const ushort2*)&W11l[g];
        }
        __syncthreads();

        const int kseg = ks*32 + 8*lk;
        float4 a0 = *(const float4*)(aRow + kseg);
        float4 a1 = *(const float4*)(aRow + kseg + 4);
        float4 n0 = *(const float4*)(anRow + kseg);
        float4 n1 = *(const float4*)(anRow + kseg + 4);
        bf16x8 uF, vF;
        uF[0] = (short)f2bf(0.5f*(a0.x + n0.x));  vF[0] = (short)f2bf(0.5f*(a0.x - n0.x));
        uF[1] = (short)f2bf(0.5f*(a0.y + n0.y));  vF[1] = (short)f2bf(0.5f*(a0.y - n0.y));
        uF[2] = (short)f2bf(0.5f*(a0.z + n0.z));  vF[2] = (short)f2bf(0.5f*(a0.z - n0.z));
        uF[3] = (short)f2bf(0.5f*(a0.w + n0.w));  vF[3] = (short)f2bf(0.5f*(a0.w - n0.w));
        uF[4] = (short)f2bf(0.5f*(a1.x + n1.x));  vF[4] = (short)f2bf(0.5f*(a1.x - n1.x));
        uF[5] = (short)f2bf(0.5f*(a1.y + n1.y));  vF[5] = (short)f2bf(0.5f*(a1.y - n1.y));
        uF[6] = (short)f2bf(0.5f*(a1.z + n1.z));  vF[6] = (short)f2bf(0.5f*(a1.z - n1.z));
        uF[7] = (short)f2bf(0.5f*(a1.w + n1.w));  vF[7] = (short)f2bf(0.5f*(a1.w - n1.w));

        #pragma unroll
        for (int t = 0; t < 6; ++t) {
            int wb = (16*t + lr)*48 + 8*lk;
            bf16x8 bh = *(const bf16x8*)&Wh_A[wb];
            T1[t] = __builtin_amdgcn_mfma_f32_16x16x32_bf16(uF, bh, T1[t], 0, 0, 0);
            bf16x8 bl = *(const bf16x8*)&Wl_A[wb];
            T1[t] = __builtin_amdgcn_mfma_f32_16x16x32_bf16(uF, bl, T1[t], 0, 0, 0);
            bf16x8 ch = *(const bf16x8*)&Wh_B[wb];
            T2[t] = __builtin_amdgcn_mfma_f32_16x16x32_bf16(vF, ch, T2[t], 0, 0, 0);
            bf16x8 cl = *(const bf16x8*)&Wl_B[wb];
            T2[t] = __builtin_amdgcn_mfma_f32_16x16x32_bf16(vF, cl, T2[t], 0, 0, 0);
        }
    }

    #pragma unroll
    for (int t = 0; t < 6; ++t) {
        float bk = b1[(0*NB + n)*BS + 16*t + lr];
        float bn = b1[(1*NB + n)*BS + 16*t + lr];
        #pragma unroll
        for (int r = 0; r < 4; ++r) {
            float ok = fmaxf(T1[t][r] + T2[t][r] + bk, 0.f);
            float on = fmaxf(T1[t][r] - T2[t][r] + bn, 0.f);
            int pl = 16*wv + 4*lk + r;
            PMp[pl*104 + 16*t + lr] = f2bf(ok + on);
            PMm[pl*104 + 16*t + lr] = f2bf(ok - on);
        }
    }

    f32x4 S[6];
    #pragma unroll
    for (int t = 0; t < 6; ++t) S[t] = (f32x4){0.f,0.f,0.f,0.f};
    for (int ks = 0; ks < 3; ++ks) {
        __syncthreads();
        for (int idx = tid; idx < 96*16; idx += 256) {
            int o = idx >> 4, kp = (idx & 15) << 1;
            int g = n*BS*BS + o*BS + ks*32 + kp;
            *(ushort2*)&Wh_A[o*48 + kp] = *(const ushort2*)&WKPh[g];
            *(ushort2*)&Wl_A[o*48 + kp] = *(const ushort2*)&WKPl[g];
            *(ushort2*)&Wh_B[o*48 + kp] = *(const ushort2*)&WKMh[g];
            *(ushort2*)&Wl_B[o*48 + kp] = *(const ushort2*)&WKMl[g];
        }
        __syncthreads();

        const int kseg = ks*32 + 8*lk;
        bf16x8 pF = *(const bf16x8*)&PMp[(16*wv + lr)*104 + kseg];
        bf16x8 mF = *(const bf16x8*)&PMm[(16*wv + lr)*104 + kseg];
        #pragma unroll
        for (int t = 0; t < 6; ++t) {
            int wb = (16*t + lr)*48 + 8*lk;
            bf16x8 bh = *(const bf16x8*)&Wh_A[wb];
            S[t] = __builtin_amdgcn_mfma_f32_16x16x32_bf16(pF, bh, S[t], 0, 0, 0);
            bf16x8 bl = *(const bf16x8*)&Wl_A[wb];
            S[t] = __builtin_amdgcn_mfma_f32_16x16x32_bf16(pF, bl, S[t], 0, 0, 0);
            bf16x8 ch = *(const bf16x8*)&Wh_B[wb];
            S[t] = __builtin_amdgcn_mfma_f32_16x16x32_bf16(mF, ch, S[t], 0, 0, 0);
            bf16x8 cl = *(const bf16x8*)&Wl_B[wb];
            S[t] = __builtin_amdgcn_mfma_f32_16x16x32_bf16(mF, cl, S[t], 0, 0, 0);
        }
    }

    #pragma unroll
    for (int t = 0; t < 6; ++t) {
        float be = BEFF[n*BS + 16*t + lr];
        #pragma unroll
        for (int r = 0; r < 4; ++r) {
            float v = S[t][r] + be;
            float av2 = fabsf(v) - 0.01f;
            float sv = (av2 > 0.f) ? copysignf(av2, v) : 0.f;
            int pt = P0 + 16*wv + 4*lk + r;
            sout[(size_t)pt*CC + n*BS + 16*t + lr] = sv;
        }
    }
}

// ---------------------------------------------------------------------------
// P7 (v4): register-resident DIF FFT, one LDS transpose, 2 barriers.
// Input spectrum now packed bf16x2. Math unchanged from verified round 11.
// ---------------------------------------------------------------------------
__global__ __launch_bounds__(256) void k_p7(
    const unsigned* __restrict__ A, const float* __restrict__ x,
    float* __restrict__ out)
{
    const int tid = threadIdx.x;
    const int row = blockIdx.y;           // 0..255 = b*HH+h
    const int c0 = blockIdx.x * 16;
    __shared__ float2 tw[128];            // e^{-2pi i t/256}, t<128
    __shared__ float2 buf[16*257];        // 32.9 KB transpose buffer

    if (tid < 128) {
        float sn, cs; sincosf(TWOPI*(float)tid/256.f, &sn, &cs);
        tw[tid] = make_float2(cs, -sn);
    }
    const int l  = tid & 15;              // line (channel)
    const int tg = tid >> 4;              // 0..15

    // load: p[m] = spectrum at index i = tg + 16m (zero-pad w >= 65)
    float2 p[16];
    const unsigned* Ar = A + (size_t)row * WKEPT * CC + c0;
    #pragma unroll
    for (int m = 0; m < 16; ++m) {
        int w = tg + 16*m;
        p[m] = (w < WKEPT) ? bf2c(Ar[(size_t)w*CC + l]) : make_float2(0.f, 0.f);
    }
    __syncthreads();   // tw ready

    // ---- stages st=0..3 (h = 128,64,32,16): thread-local on i = tg+16m ----
    #pragma unroll
    for (int st = 0; st < 4; ++st) {
        const int h16 = 8 >> st;          // pair distance in m
        #pragma unroll
        for (int g = 0; g < (1 << st); ++g) {
            #pragma unroll
            for (int ml = 0; ml < (8 >> st); ++ml) {
                int m = g*2*h16 + ml;
                int mp = m + h16;
                float2 a = p[m], b = p[mp];
                float2 w = tw[(tg + 16*ml) << st];   // j = i&(h-1) = tg+16*ml
                float dx = a.x - b.x, dy = a.y - b.y;
                p[m]  = make_float2(a.x + b.x, a.y + b.y);
                p[mp] = make_float2(dx*w.x - dy*w.y, dx*w.y + dy*w.x);
            }
        }
    }

    // ---- transpose: i = tg+16m  ->  i = 16*tg + m ----
    #pragma unroll
    for (int m = 0; m < 16; ++m)
        buf[l*257 + tg + 16*m] = p[m];
    __syncthreads();
    #pragma unroll
    for (int m = 0; m < 16; ++m)
        p[m] = buf[l*257 + 16*tg + m];

    // ---- stages st=4..7 (h = 8,4,2,1): thread-local on i = 16*tg + m ----
    #pragma unroll
    for (int st = 4; st < 8; ++st) {
        const int h = 128 >> st;          // 8,4,2,1
        #pragma unroll
        for (int g = 0; g < (1 << (st-4)); ++g) {
            #pragma unroll
            for (int ml = 0; ml < (128 >> st); ++ml) {
                int m = g*2*h + ml;
                int mp = m + h;
                float2 a = p[m], b = p[mp];
                float2 w = tw[ml << st];             // j = i&(h-1) = ml
                float dx = a.x - b.x, dy = a.y - b.y;
                p[m]  = make_float2(a.x + b.x, a.y + b.y);
                p[mp] = make_float2(dx*w.x - dy*w.y, dx*w.y + dy*w.x);
            }
        }
    }

    // ---- epilogue: w = brev8(i) ----
    const float scale = 1.0f / 50331648.0f;
    const size_t obase = (size_t)row * WW * CC + c0;
    #pragma unroll
    for (int m = 0; m < 16; ++m) {
        int i = 16*tg + m;
        int w = (int)(__brev((unsigned)i) >> 24);
        size_t g = obase + (size_t)w*CC + l;
        out[g] = fmaf(p[m].x + p[m].y, scale, x[g]);
    }
}

// ---------------------------------------------------------------------------
// Launch. ws layout:
//   floats: a_real [0, NPTS*CC) | s_real [NPTS*CC, 2*NPTS*CC) | BEFF | weights
//   Abuf (bf16x2 uint, NPTS*CC entries = 51 MB) ALIASES the a_real region —
//   lifetimes disjoint: Abuf#1 (p1->cfft1) ends before hb_c2a writes a_real;
//   Abuf#2 (cfft2->p7) starts after mlp consumed a_real.
//   Bc (bf16x2 uint) lives in d_out; consumed by cfft2 before p7 overwrites.
// ---------------------------------------------------------------------------
extern "C" void kernel_launch(void* const* d_in, const int* in_sizes, int n_in,
                              void* d_out, int out_size, void* d_ws, size_t ws_size,
                              hipStream_t stream)
{
    (void)in_sizes; (void)n_in; (void)out_size; (void)ws_size;
    const float* x  = (const float*)d_in[0];
    const float* w1 = (const float*)d_in[1];
    const float* b1 = (const float*)d_in[2];
    const float* w2 = (const float*)d_in[3];
    const float* b2 = (const float*)d_in[4];

    float*    ws     = (float*)d_ws;
    float*    a_real = ws;
    float*    s_real = ws + (size_t)NPTS*CC;
    unsigned* Abuf   = (unsigned*)d_ws;            // aliases a_real (see above)
    float*    BEFF   = ws + 2*(size_t)NPTS*CC;
    unsigned short* Wq = (unsigned short*)(BEFF + NB*BS);
    const size_t WSZ = (size_t)NB*BS*BS;
    unsigned short* W10h = Wq + 0*WSZ;
    unsigned short* W10l = Wq + 1*WSZ;
    unsigned short* W11h = Wq + 2*WSZ;
    unsigned short* W11l = Wq + 3*WSZ;
    unsigned short* WKPh = Wq + 4*WSZ;
    unsigned short* WKPl = Wq + 5*WSZ;
    unsigned short* WKMh = Wq + 6*WSZ;
    unsigned short* WKMl = Wq + 7*WSZ;

    unsigned* Bc   = (unsigned*)d_out;
    float*    outf = (float*)d_out;

    k_weights<<<dim3(NB), dim3(256), 0, stream>>>(
        w1, w2, b2, W10h, W10l, W11h, W11l, WKPh, WKPl, WKMh, WKMl, BEFF);
    k_p1     <<<dim3(48, 256), dim3(256), 0, stream>>>(x, Abuf);
    k_cfft   <<<dim3(NPTS/LPB), dim3(256), 0, stream>>>(Abuf, Bc);
    k_hb_c2a <<<dim3(96, WKEPT), dim3(256), 0, stream>>>(Bc, a_real);
    k_mlp    <<<dim3(260, NB), dim3(256), 0, stream>>>(
        a_real, x, W10h, W10l, W11h, W11l, WKPh, WKPl, WKMh, WKMl,
        b1, BEFF, s_real);
    k_hb_s2c <<<dim3(48, WKEPT), dim3(256), 0, stream>>>(s_real, Bc);
    k_cfft   <<<dim3(NPTS/LPB), dim3(256), 0, stream>>>(Bc, Abuf);
    k_p7     <<<dim3(48, 256), dim3(256), 0, stream>>>(Abuf, x, outf);
}